// Round 1
// 2719.200 us; speedup vs baseline: 1.1070x; 1.1070x over previous
//
#include <hip/hip_runtime.h>

// ---------------------------------------------------------------------------
// QLlamaAttention: mixed 4/6/8-bit block fake-quant qlinear (q,k,v,o) + RoPE +
// causal SDPA.  All matmuls use bf16 "split" (hi+lo) MFMA for ~2^-17 relative
// error (needed: attention output is re-quantized; round() flips amplify any
// error by the 4-bit scale step).
//
// R3 -> R4: flash_attn rebuilt as T3 2-phase pipelined kernel:
//   - KVBLK=32 double-buffered K/V in LDS, staged via global_load_lds (16B)
//     with XOR-swizzled per-lane global source (linear LDS dest)
//   - one raw s_barrier + manual vmcnt(0) per step (was 3 __syncthreads with
//     full drains)
//   - dedicated P-transpose slots (no sK aliasing barrier)
//   - V fragments hoisted out of the m loop (halves V ds_reads)
//   - causal mask only on the boundary step; wave-uniform skip of fully
//     masked steps; heavy-q-tiles-first + bh-per-XCD block remap
// ---------------------------------------------------------------------------

typedef __bf16 bf16_t;
typedef __bf16 bf16x8 __attribute__((ext_vector_type(8)));
typedef float f32x4 __attribute__((ext_vector_type(4)));

#define MFMA16(a, b, c) __builtin_amdgcn_mfma_f32_16x16x32_bf16(a, b, c, 0, 0, 0)

__device__ __forceinline__ void split_bf16(float x, bf16_t& h, bf16_t& l) {
    h = (bf16_t)x;
    l = (bf16_t)(x - (float)h);
}

typedef const __attribute__((address_space(1))) void glb_v;
typedef __attribute__((address_space(3))) void lds_v;

__device__ __forceinline__ void gl_lds16(const void* g, void* l) {
    __builtin_amdgcn_global_load_lds((glb_v*)g, (lds_v*)l, 16, 0, 0);
}

// ---------------------------------------------------------------------------
// Elementwise mixed block fake-quant of a [4096 x 4096] matrix.
// ---------------------------------------------------------------------------
__global__ void quant_split(const float* __restrict__ srcf,
                            const bf16_t* __restrict__ shi, const bf16_t* __restrict__ slo,
                            const int* __restrict__ rid, int src_split, int gather,
                            bf16_t* __restrict__ dhi, bf16_t* __restrict__ dlo) {
    long idx = (long)blockIdx.x * 256 + threadIdx.x;
    int col = (int)(idx & 4095);
    long row = idx >> 12;
    int g = gather ? rid[col] : col;
    long si = row * 4096 + g;
    float v = src_split ? ((float)shi[si] + (float)slo[si]) : srcf[si];
    float a = fabsf(v);
#pragma unroll
    for (int off = 1; off < 32; off <<= 1) a = fmaxf(a, __shfl_xor(a, off, 32));
    float qmax = (col < 2560) ? 7.0f : (col < 3584 ? 31.0f : 127.0f);
    float scale = fmaxf(a / qmax, 1e-8f);
    float q = rintf(v * (1.0f / scale));
    q = fminf(fmaxf(q, -qmax), qmax);
    float dq = q * scale;
    bf16_t h, l;
    split_bf16(dq, h, l);
    dhi[idx] = h;
    dlo[idx] = l;
}

// ---------------------------------------------------------------------------
// GEMM C[4096,4096] = Aq * Bq^T.  128x128 tile, BK=32, 3 split passes.
// ---------------------------------------------------------------------------
template<int AQ, int ASPL, int OSPL>
__global__ __launch_bounds__(256, 2) void gemm_bt(
    const float* __restrict__ Af,
    const bf16_t* __restrict__ AHi, const bf16_t* __restrict__ ALo,
    const int* __restrict__ rid,
    const bf16_t* __restrict__ BHi, const bf16_t* __restrict__ BLo,
    bf16_t* __restrict__ OHi, bf16_t* __restrict__ OLo,
    float* __restrict__ Of) {
    constexpr int K = 4096, N = 4096;
    __shared__ __align__(16) bf16_t sAh[128 * 32];
    __shared__ __align__(16) bf16_t sAl[128 * 32];
    __shared__ __align__(16) bf16_t sBh[128 * 32];
    __shared__ __align__(16) bf16_t sBl[128 * 32];

    const int tid = threadIdx.x;
    const int bx = blockIdx.x & 31, by = blockIdx.x >> 5;
    const int rowBase = by << 7, colBase = bx << 7;
    const int lane = tid & 63, wave = tid >> 6;
    const int wr = (wave >> 1) << 6, wc = (wave & 1) << 6;
    const int n16 = lane & 15, quad = lane >> 4;

    f32x4 acc[4][4];
#pragma unroll
    for (int m = 0; m < 4; ++m)
#pragma unroll
        for (int n = 0; n < 4; ++n) acc[m][n] = (f32x4){0.f, 0.f, 0.f, 0.f};

    for (int k0 = 0; k0 < K; k0 += 32) {
        __syncthreads();
        if (AQ) {
            float qmax = (k0 < 2560) ? 7.0f : (k0 < 3584 ? 31.0f : 127.0f);
#pragma unroll
            for (int i = 0; i < 2; ++i) {
                int l = i * 256 + tid, r = l >> 2, cb = (l & 3) << 3;
                long rowoff = (long)(rowBase + r) * K;
                const int* rp = rid + k0 + cb;
                float v[8];
                float am = 0.f;
#pragma unroll
                for (int j = 0; j < 8; ++j) {
                    int gg = rp[j];
                    float xv = ASPL ? ((float)AHi[rowoff + gg] + (float)ALo[rowoff + gg])
                                    : Af[rowoff + gg];
                    v[j] = xv;
                    am = fmaxf(am, fabsf(xv));
                }
                am = fmaxf(am, __shfl_xor(am, 1, 64));
                am = fmaxf(am, __shfl_xor(am, 2, 64));
                float scale = fmaxf(am / qmax, 1e-8f);
                float inv = 1.0f / scale;
                bf16x8 hv, lv;
#pragma unroll
                for (int j = 0; j < 8; ++j) {
                    float q = rintf(v[j] * inv);
                    q = fminf(fmaxf(q, -qmax), qmax);
                    float dq = q * scale;
                    bf16_t h, l2;
                    split_bf16(dq, h, l2);
                    hv[j] = h;
                    lv[j] = l2;
                }
                *(bf16x8*)&sAh[l << 3] = hv;
                *(bf16x8*)&sAl[l << 3] = lv;
            }
        } else {
#pragma unroll
            for (int i = 0; i < 2; ++i) {
                int l = i * 256 + tid, r = l >> 2, cb = (l & 3) << 3;
                long off = (long)(rowBase + r) * K + k0 + cb;
                *(uint4*)&sAh[l << 3] = *(const uint4*)&AHi[off];
                *(uint4*)&sAl[l << 3] = *(const uint4*)&ALo[off];
            }
        }
#pragma unroll
        for (int i = 0; i < 2; ++i) {
            int l = i * 256 + tid, r = l >> 2, cb = (l & 3) << 3;
            long off = (long)(colBase + r) * K + k0 + cb;
            *(uint4*)&sBh[l << 3] = *(const uint4*)&BHi[off];
            *(uint4*)&sBl[l << 3] = *(const uint4*)&BLo[off];
        }
        __syncthreads();

        bf16x8 ah[4], al[4], bh[4], bl[4];
#pragma unroll
        for (int m = 0; m < 4; ++m) {
            int row = wr + (m << 4) + n16;
            ah[m] = *(const bf16x8*)&sAh[(row << 5) + (quad << 3)];
            al[m] = *(const bf16x8*)&sAl[(row << 5) + (quad << 3)];
        }
#pragma unroll
        for (int n = 0; n < 4; ++n) {
            int row = wc + (n << 4) + n16;
            bh[n] = *(const bf16x8*)&sBh[(row << 5) + (quad << 3)];
            bl[n] = *(const bf16x8*)&sBl[(row << 5) + (quad << 3)];
        }
#pragma unroll
        for (int m = 0; m < 4; ++m)
#pragma unroll
            for (int n = 0; n < 4; ++n) {
                acc[m][n] = MFMA16(ah[m], bh[n], acc[m][n]);
                acc[m][n] = MFMA16(ah[m], bl[n], acc[m][n]);
                acc[m][n] = MFMA16(al[m], bh[n], acc[m][n]);
            }
    }

#pragma unroll
    for (int m = 0; m < 4; ++m)
#pragma unroll
        for (int n = 0; n < 4; ++n) {
            int row = rowBase + wr + (m << 4) + (quad << 2);
            int col = colBase + wc + (n << 4) + n16;
#pragma unroll
            for (int r = 0; r < 4; ++r) {
                if (OSPL) {
                    bf16_t h, l;
                    split_bf16(acc[m][n][r], h, l);
                    OHi[(long)(row + r) * N + col] = h;
                    OLo[(long)(row + r) * N + col] = l;
                } else {
                    Of[(long)(row + r) * N + col] = acc[m][n][r];
                }
            }
        }
}

// ---------------------------------------------------------------------------
// RoPE in place on split q,k.
// ---------------------------------------------------------------------------
__global__ void rope2(bf16_t* __restrict__ qh, bf16_t* __restrict__ ql,
                      bf16_t* __restrict__ kh, bf16_t* __restrict__ kl,
                      const int* __restrict__ pos) {
    int t = blockIdx.x;
    int tid = threadIdx.x;
    __shared__ float cs[64], sn[64];
    if (tid < 64) {
        float invf = (float)pow(10000.0, -(double)tid / 64.0);
        float ang = (float)pos[t] * invf;
        cs[tid] = (float)cos((double)ang);
        sn[tid] = (float)sin((double)ang);
    }
    __syncthreads();
#pragma unroll
    for (int i = 0; i < 8; ++i) {
        int l = i * 256 + tid;
        int hh = l >> 6, d = l & 63;
        long base = (long)t * 4096 + hh * 128 + d;
        float c = cs[d], s = sn[d];
        float a0 = (float)qh[base] + (float)ql[base];
        float a1 = (float)qh[base + 64] + (float)ql[base + 64];
        float r0 = a0 * c - a1 * s, r1 = a1 * c + a0 * s;
        bf16_t x, y;
        split_bf16(r0, x, y); qh[base] = x;      ql[base] = y;
        split_bf16(r1, x, y); qh[base + 64] = x; ql[base + 64] = y;
        float b0 = (float)kh[base] + (float)kl[base];
        float b1 = (float)kh[base + 64] + (float)kl[base + 64];
        r0 = b0 * c - b1 * s; r1 = b1 * c + b0 * s;
        split_bf16(r0, x, y); kh[base] = x;      kl[base] = y;
        split_bf16(r1, x, y); kh[base + 64] = x; kl[base + 64] = y;
    }
}

// ---------------------------------------------------------------------------
// Transpose split V [tok, h*128+d] -> vT[(b*32+h)*128+d][s], both planes.
// ---------------------------------------------------------------------------
__global__ void transpose_vt(const ushort* __restrict__ vh, const ushort* __restrict__ vl,
                             ushort* __restrict__ th, ushort* __restrict__ tl) {
    __shared__ ushort t0[64][68];
    __shared__ ushort t1[64][68];
    int ct = blockIdx.x, tt = blockIdx.y, tid = threadIdx.x;
#pragma unroll
    for (int i = 0; i < 16; ++i) {
        int l = i * 256 + tid, r = l >> 6, c = l & 63;
        long idx = (long)(tt * 64 + r) * 4096 + ct * 64 + c;
        t0[r][c] = vh[idx];
        t1[r][c] = vl[idx];
    }
    __syncthreads();
#pragma unroll
    for (int i = 0; i < 16; ++i) {
        int l = i * 256 + tid, dr = l >> 6, sc = l & 63;
        int colg = ct * 64 + dr, hh = colg >> 7, dl = colg & 127;
        int tok = tt * 64 + sc, b = tok >> 11, s = tok & 2047;
        long o = (long)((b * 32 + hh) * 128 + dl) * 2048 + s;
        th[o] = t0[sc][dr];
        tl[o] = t1[sc][dr];
    }
}

// ---------------------------------------------------------------------------
// Causal flash attention, 2-phase pipelined (T3 minimum recipe).
//
// Grid: 1024 1-D blocks remapped so each XCD owns 8 (b,h) groups (K/V L2
// reuse) and long q-tiles launch first (causal-length tail fix).
// Block = 256 threads = 4 waves; wave w owns 32 q rows (2 m-frags of 16).
// Per 32-key step: the NEXT K/V tile is staged via global_load_lds (16B,
// XOR-swizzled global source, linear LDS dest) into the other buffer while
// this step's QK^T / softmax / PV run; one raw s_barrier + manual vmcnt(0)
// per step.  LDS: 2 x 32KB K/V buffers + 10KB dedicated P slots = 75.7KB
// -> 2 blocks/CU.
//
// Swizzles (writer source addr and ds_read addr use the SAME XOR):
//   K  [32][128] bf16, 256B rows: byte ^= (row&7)<<4  -> conflict-free b128
//   V^T[128][32] bf16,  64B rows: byte ^= (row&3)<<4  -> 2-way (free)
// ---------------------------------------------------------------------------
__global__ __launch_bounds__(256, 2) void flash_attn3(
    const bf16_t* __restrict__ qhp, const bf16_t* __restrict__ qlp,
    const bf16_t* __restrict__ khp, const bf16_t* __restrict__ klp,
    const bf16_t* __restrict__ vth, const bf16_t* __restrict__ vtl,
    bf16_t* __restrict__ ohi, bf16_t* __restrict__ olo) {
    __shared__ __align__(16) char smem[75776];

    // block remap: xcd = bid&7 (round-robin dispatch), 8 bh per xcd,
    // q-tiles heavy-first within each bh.
    const int bid = blockIdx.x;
    const int xcd = bid & 7, ixd = bid >> 3;
    const int bh = (xcd << 3) + (ixd >> 4);
    const int qt = 15 - (ixd & 15);
    const int b = bh >> 5, h = bh & 31;
    const int tid = threadIdx.x;
    const int wave = tid >> 6, lane = tid & 63;
    const int n16 = lane & 15, quad = lane >> 4;
    const long tokB = (long)b * 2048;
    const int q0 = qt * 128 + wave * 32;
    const float scale = 0.08838834764831845f;   // 1/sqrt(128)

    // dedicated per-wave P transpose slots (16 x 40 x hi/lo), 80B rows
    bf16_t (*pH)[40] = (bf16_t (*)[40])(smem + 65536 + wave * 2560);
    bf16_t (*pL)[40] = (bf16_t (*)[40])(smem + 65536 + wave * 2560 + 1280);

    // ---- Q fragments, held in registers for the whole kernel ----
    bf16x8 qhF[2][4], qlF[2][4];
#pragma unroll
    for (int m = 0; m < 2; ++m) {
        long qoff = (tokB + q0 + m * 16 + n16) * 4096 + h * 128 + quad * 8;
#pragma unroll
        for (int f = 0; f < 4; ++f) {
            qhF[m][f] = *(const bf16x8*)&qhp[qoff + f * 32];
            qlF[m][f] = *(const bf16x8*)&qlp[qoff + f * 32];
        }
    }

    // ---- staging geometry (per-thread constants) ----
    // K: plane 8KB = 32 rows x 256B; wave w stages rows w*8..w*8+7 (2 issues).
    const int kr0 = wave * 8 + quad;                         // c=0 row (c=1: +4)
    const int kc0 = ((((lane & 15) << 4) ^ (quad << 4)) >> 1);        // elems
    const int kc1 = ((((lane & 15) << 4) ^ ((4 + quad) << 4)) >> 1);
    const int kd0 = kr0 * 256 + ((lane & 15) << 4);          // lds byte, plane-rel
    // V: plane 8KB = 128 rows x 64B; wave w stages rows w*32..w*32+31 (2 issues).
    const int vr0 = wave * 32 + (lane >> 2);                 // c=0 row (c=1: +16)
    const int vc0 = ((((lane & 3) << 4) ^ (((lane >> 2) & 3) << 4)) >> 1);
    const int vd0 = vr0 * 64 + ((lane & 3) << 4);
    const long vrow_g = (long)(bh * 128 + vr0) * 2048;

#define STAGE(BUF, KB) do {                                                   \
    char* _bb = smem + ((BUF) << 15);                                         \
    const long _kt = tokB + (long)(KB) * 32;                                  \
    const long _g0 = (_kt + kr0) * 4096 + h * 128;                            \
    gl_lds16(khp + _g0 + kc0,           _bb + kd0);                           \
    gl_lds16(klp + _g0 + kc0,           _bb + 8192 + kd0);                    \
    gl_lds16(khp + _g0 + 4 * 4096 + kc1, _bb + 1024 + kd0);                   \
    gl_lds16(klp + _g0 + 4 * 4096 + kc1, _bb + 8192 + 1024 + kd0);            \
    const long _v0 = vrow_g + (KB) * 32 + vc0;                                \
    gl_lds16(vth + _v0,                 _bb + 16384 + vd0);                   \
    gl_lds16(vtl + _v0,                 _bb + 24576 + vd0);                   \
    gl_lds16(vth + _v0 + 16 * 2048,     _bb + 16384 + 1024 + vd0);            \
    gl_lds16(vtl + _v0 + 16 * 2048,     _bb + 24576 + 1024 + vd0);            \
} while (0)

    f32x4 o[2][8];
#pragma unroll
    for (int m = 0; m < 2; ++m)
#pragma unroll
        for (int dc = 0; dc < 8; ++dc) o[m][dc] = (f32x4){0.f, 0.f, 0.f, 0.f};
    float m_i[2][4], l_i[2][4];
#pragma unroll
    for (int m = 0; m < 2; ++m)
#pragma unroll
        for (int r = 0; r < 4; ++r) { m_i[m][r] = -1e30f; l_i[m][r] = 0.f; }

    const int nkb = 4 * qt + 4;
    const int lastkb = 4 * qt + wave;   // last step with any unmasked key

    // prologue: stage buf0, drain, barrier
    STAGE(0, 0);
    asm volatile("s_waitcnt vmcnt(0)" ::: "memory");
    __builtin_amdgcn_s_barrier();
    asm volatile("" ::: "memory");

    for (int kb = 0; kb < nkb; ++kb) {
        if (kb + 1 < nkb) STAGE((kb + 1) & 1, kb + 1);   // async, lands by next barrier

        if (kb <= lastkb) {
            const char* bK = smem + ((kb & 1) << 15);
            const char* bV = bK + 16384;

            // ---- scores: 2m x 2nt frags, 3-pass split ----
            f32x4 s[2][2];
            const int rswz = (n16 & 7) << 4;
#pragma unroll
            for (int nt = 0; nt < 2; ++nt) {
                const int krow = nt * 16 + n16;
                bf16x8 kh[4], kl[4];
#pragma unroll
                for (int f = 0; f < 4; ++f) {
                    const int cb = ((f << 6) | (quad << 4)) ^ rswz;
                    kh[f] = *(const bf16x8*)(bK + krow * 256 + cb);
                    kl[f] = *(const bf16x8*)(bK + 8192 + krow * 256 + cb);
                }
#pragma unroll
                for (int m = 0; m < 2; ++m) {
                    f32x4 sc = (f32x4){0.f, 0.f, 0.f, 0.f};
#pragma unroll
                    for (int f = 0; f < 4; ++f) {
                        sc = MFMA16(qhF[m][f], kh[f], sc);
                        sc = MFMA16(qhF[m][f], kl[f], sc);
                        sc = MFMA16(qlF[m][f], kh[f], sc);
                    }
                    s[m][nt] = sc;
                }
            }

            // ---- scale; causal mask only on the boundary step ----
            if (kb == lastkb) {
                const int key0 = kb * 32 + n16;
#pragma unroll
                for (int m = 0; m < 2; ++m)
#pragma unroll
                    for (int nt = 0; nt < 2; ++nt)
#pragma unroll
                        for (int r = 0; r < 4; ++r) {
                            int qrow = q0 + m * 16 + quad * 4 + r;
                            s[m][nt][r] = (key0 + nt * 16 <= qrow) ? s[m][nt][r] * scale
                                                                   : -1e30f;
                        }
            } else {
#pragma unroll
                for (int m = 0; m < 2; ++m)
#pragma unroll
                    for (int nt = 0; nt < 2; ++nt)
#pragma unroll
                        for (int r = 0; r < 4; ++r) s[m][nt][r] *= scale;
            }

            // ---- online softmax (rows live in 16 contiguous lanes) ----
            float alpha[2][4];
#pragma unroll
            for (int m = 0; m < 2; ++m)
#pragma unroll
                for (int r = 0; r < 4; ++r) {
                    float mx = fmaxf(s[m][0][r], s[m][1][r]);
#pragma unroll
                    for (int off = 1; off < 16; off <<= 1) mx = fmaxf(mx, __shfl_xor(mx, off, 64));
                    float mnew = fmaxf(m_i[m][r], mx);
                    alpha[m][r] = expf(m_i[m][r] - mnew);
                    m_i[m][r] = mnew;
                    float p0 = expf(s[m][0][r] - mnew);
                    float p1 = expf(s[m][1][r] - mnew);
                    s[m][0][r] = p0;
                    s[m][1][r] = p1;
                    float sum = p0 + p1;
#pragma unroll
                    for (int off = 1; off < 16; off <<= 1) sum += __shfl_xor(sum, off, 64);
                    l_i[m][r] = l_i[m][r] * alpha[m][r] + sum;
                }

            // ---- P -> private LDS slot (C->A transpose), both m ----
            bf16x8 ph2[2], pl2[2];
#pragma unroll
            for (int m = 0; m < 2; ++m) {
#pragma unroll
                for (int nt = 0; nt < 2; ++nt)
#pragma unroll
                    for (int r = 0; r < 4; ++r) {
                        bf16_t hh2, ll2;
                        split_bf16(s[m][nt][r], hh2, ll2);
                        pH[quad * 4 + r][nt * 16 + n16] = hh2;
                        pL[quad * 4 + r][nt * 16 + n16] = ll2;
                    }
                ph2[m] = *(const bf16x8*)&pH[n16][quad * 8];
                pl2[m] = *(const bf16x8*)&pL[n16][quad * 8];
            }

            // ---- PV: each V frag loaded once, used by both m ----
#pragma unroll
            for (int dc = 0; dc < 8; ++dc) {
                const int vrow = dc * 16 + n16;
                const int vcb = ((quad ^ (n16 & 3)) << 4);
                bf16x8 vh = *(const bf16x8*)(bV + vrow * 64 + vcb);
                bf16x8 vl = *(const bf16x8*)(bV + 8192 + vrow * 64 + vcb);
#pragma unroll
                for (int m = 0; m < 2; ++m) {
#pragma unroll
                    for (int r = 0; r < 4; ++r) o[m][dc][r] *= alpha[m][r];
                    o[m][dc] = MFMA16(ph2[m], vh, o[m][dc]);
                    o[m][dc] = MFMA16(ph2[m], vl, o[m][dc]);
                    o[m][dc] = MFMA16(pl2[m], vh, o[m][dc]);
                }
            }
        }

        // drain this wave's DMA for kb+1, then one barrier:
        //  - all waves' stage of buf[(kb+1)&1] landed
        //  - all waves done reading buf[kb&1] (safe to DMA it next iter)
        asm volatile("s_waitcnt vmcnt(0)" ::: "memory");
        __builtin_amdgcn_s_barrier();
        asm volatile("" ::: "memory");
    }
#undef STAGE

    // ---- normalize + write split ----
#pragma unroll
    for (int m = 0; m < 2; ++m)
#pragma unroll
        for (int r = 0; r < 4; ++r) {
            float invl = 1.0f / l_i[m][r];
            long row = tokB + q0 + m * 16 + quad * 4 + r;
#pragma unroll
            for (int dc = 0; dc < 8; ++dc) {
                bf16_t hh2, ll2;
                split_bf16(o[m][dc][r] * invl, hh2, ll2);
                ohi[row * 4096 + h * 128 + dc * 16 + n16] = hh2;
                olo[row * 4096 + h * 128 + dc * 16 + n16] = ll2;
            }
        }
}

// ---------------------------------------------------------------------------
// Launcher.  ws regions (64 MB each): W0 weights-split / vT, W1 q-split /
// Wo-split, W2 k-split / final fp32, OUT = d_out as v-split then attn-split
// scratch.  W3 only if ws_size >= 256 MB (pre-quantized activation cache).
// ---------------------------------------------------------------------------
extern "C" void kernel_launch(void* const* d_in, const int* in_sizes, int n_in,
                              void* d_out, int out_size, void* d_ws, size_t ws_size,
                              hipStream_t stream) {
    const float* x  = (const float*)d_in[0];
    const float* Wq = (const float*)d_in[1];
    const float* Wk = (const float*)d_in[2];
    const float* Wv = (const float*)d_in[3];
    const float* Wo = (const float*)d_in[4];
    const int* pos  = (const int*)d_in[5];
    const int* rid  = (const int*)d_in[6];

    const size_t MB = 1024ull * 1024ull;
    char* ws = (char*)d_ws;
    bf16_t* W0h = (bf16_t*)(ws);
    bf16_t* W0l = (bf16_t*)(ws + 32 * MB);
    bf16_t* W1h = (bf16_t*)(ws + 64 * MB);
    bf16_t* W1l = (bf16_t*)(ws + 96 * MB);
    bf16_t* W2h = (bf16_t*)(ws + 128 * MB);
    bf16_t* W2l = (bf16_t*)(ws + 160 * MB);
    bf16_t* OUh = (bf16_t*)d_out;
    bf16_t* OUl = (bf16_t*)((char*)d_out + 32 * MB);
    bf16_t* W3h = (bf16_t*)(ws + 192 * MB);
    bf16_t* W3l = (bf16_t*)(ws + 224 * MB);
    const bool fast = (ws_size >= 256 * MB);

    const int QG = 65536;

    // ---- q = xq @ Wq^T ----
    quant_split<<<QG, 256, 0, stream>>>(Wq, nullptr, nullptr, rid, 0, 0, W0h, W0l);
    if (fast) {
        quant_split<<<QG, 256, 0, stream>>>(x, nullptr, nullptr, rid, 0, 1, W3h, W3l);
        gemm_bt<0, 1, 1><<<1024, 256, 0, stream>>>(nullptr, W3h, W3l, rid, W0h, W0l, W1h, W1l, nullptr);
    } else {
        gemm_bt<1, 0, 1><<<1024, 256, 0, stream>>>(x, nullptr, nullptr, rid, W0h, W0l, W1h, W1l, nullptr);
    }
    // ---- k ----
    quant_split<<<QG, 256, 0, stream>>>(Wk, nullptr, nullptr, rid, 0, 0, W0h, W0l);
    if (fast)
        gemm_bt<0, 1, 1><<<1024, 256, 0, stream>>>(nullptr, W3h, W3l, rid, W0h, W0l, W2h, W2l, nullptr);
    else
        gemm_bt<1, 0, 1><<<1024, 256, 0, stream>>>(x, nullptr, nullptr, rid, W0h, W0l, W2h, W2l, nullptr);
    // ---- v (into d_out scratch) ----
    quant_split<<<QG, 256, 0, stream>>>(Wv, nullptr, nullptr, rid, 0, 0, W0h, W0l);
    if (fast)
        gemm_bt<0, 1, 1><<<1024, 256, 0, stream>>>(nullptr, W3h, W3l, rid, W0h, W0l, OUh, OUl, nullptr);
    else
        gemm_bt<1, 0, 1><<<1024, 256, 0, stream>>>(x, nullptr, nullptr, rid, W0h, W0l, OUh, OUl, nullptr);

    rope2<<<4096, 256, 0, stream>>>(W1h, W1l, W2h, W2l, pos);

    transpose_vt<<<dim3(64, 64), 256, 0, stream>>>((const ushort*)OUh, (const ushort*)OUl,
                                                   (ushort*)W0h, (ushort*)W0l);

    flash_attn3<<<1024, 256, 0, stream>>>(W1h, W1l, W2h, W2l, W0h, W0l, OUh, OUl);

    // ---- out = attnq @ Wo^T ----
    quant_split<<<QG, 256, 0, stream>>>(Wo, nullptr, nullptr, rid, 0, 0, W1h, W1l);
    if (fast) {
        quant_split<<<QG, 256, 0, stream>>>(nullptr, OUh, OUl, rid, 1, 1, W3h, W3l);
        gemm_bt<0, 1, 0><<<1024, 256, 0, stream>>>(nullptr, W3h, W3l, rid, W1h, W1l, nullptr, nullptr, (float*)d_out);
    } else {
        float* outf = (float*)W2h;   // k-split dead
        gemm_bt<1, 1, 0><<<1024, 256, 0, stream>>>(nullptr, OUh, OUl, rid, W1h, W1l, nullptr, nullptr, outf);
        hipMemcpyAsync(d_out, outf, 64 * MB, hipMemcpyDeviceToDevice, stream);
    }

    (void)in_sizes; (void)n_in; (void)out_size;
}

// Round 2
// 2532.647 us; speedup vs baseline: 1.1885x; 1.0737x over previous
//
#include <hip/hip_runtime.h>

// ---------------------------------------------------------------------------
// QLlamaAttention: mixed 4/6/8-bit block fake-quant qlinear (q,k,v,o) + RoPE +
// causal SDPA.
//
// R4 -> R5: qlinear GEMMs rebuilt on EXACT integer arithmetic:
//   dq = q * scale with integer |q| <= 127  ->  q is exact in bf16, and a
//   16x16x32 bf16 MFMA spans exactly one 32-elem scale block, accumulating
//   sum(q_a*q_b) EXACTLY in fp32 (< 2^24).  So one MFMA pass + per-block
//   scale-FMA replaces the old 3-pass hi/lo split (3x less MFMA work, 2x
//   less LDS/HBM traffic, tighter numerics).
//   Activations stored as i8 + f32 row-block scales; weights as bf16-int +
//   scales.  Single code path (x quantized once); no final memcpy.
// Flash attention (R4's 2-phase pipelined kernel) unchanged.
// ---------------------------------------------------------------------------

typedef __bf16 bf16_t;
typedef __bf16 bf16x8 __attribute__((ext_vector_type(8)));
typedef float f32x4 __attribute__((ext_vector_type(4)));

#define MFMA16(a, b, c) __builtin_amdgcn_mfma_f32_16x16x32_bf16(a, b, c, 0, 0, 0)

__device__ __forceinline__ void split_bf16(float x, bf16_t& h, bf16_t& l) {
    h = (bf16_t)x;
    l = (bf16_t)(x - (float)h);
}

typedef const __attribute__((address_space(1))) void glb_v;
typedef __attribute__((address_space(3))) void lds_v;

__device__ __forceinline__ void gl_lds16(const void* g, void* l) {
    __builtin_amdgcn_global_load_lds((glb_v*)g, (lds_v*)l, 16, 0, 0);
}

// ---------------------------------------------------------------------------
// Mixed block fake-quant of a [4096 x 4096] matrix -> integer codes + scales.
// OUT_I8=1: codes as int8 (activations).  OUT_I8=0: codes as bf16 (weights).
// Scales: f32, [row][kb] with kb = col/32 (128 blocks per row).
// ---------------------------------------------------------------------------
template<int OUT_I8>
__global__ void quant_is(const float* __restrict__ srcf,
                         const bf16_t* __restrict__ shi, const bf16_t* __restrict__ slo,
                         const int* __restrict__ rid, int src_split, int gather,
                         signed char* __restrict__ qi8, bf16_t* __restrict__ qbf,
                         float* __restrict__ qs) {
    long idx = (long)blockIdx.x * 256 + threadIdx.x;
    int col = (int)(idx & 4095);
    long row = idx >> 12;
    int g = gather ? rid[col] : col;
    long si = row * 4096 + g;
    float v = src_split ? ((float)shi[si] + (float)slo[si]) : srcf[si];
    float a = fabsf(v);
#pragma unroll
    for (int off = 1; off < 32; off <<= 1) a = fmaxf(a, __shfl_xor(a, off, 32));
    float qmax = (col < 2560) ? 7.0f : (col < 3584 ? 31.0f : 127.0f);
    float scale = fmaxf(a / qmax, 1e-8f);
    float q = rintf(v * (1.0f / scale));
    q = fminf(fmaxf(q, -qmax), qmax);
    if (OUT_I8) qi8[idx] = (signed char)q;
    else        qbf[idx] = (bf16_t)q;
    if ((col & 31) == 0) qs[row * 128 + (col >> 5)] = scale;
}

// ---------------------------------------------------------------------------
// GEMM C[4096,4096] = (As.Aq) * (Bs.Bq)^T, exact-int inner blocks.
// 128x128 tile, BK=32 (= one scale block).  Per K-step:
//   sc = MFMA(q_a, q_b, 0)  (exact int partial, fp32)
//   acc[r] += (as[row_r] * bs[col]) * sc[r]
// A staged from i8 (reg cvt -> LDS bf16); B staged via global_load_lds.
// ---------------------------------------------------------------------------
template<int OSPL>
__global__ __launch_bounds__(256, 2) void gemm_is(
    const signed char* __restrict__ Ai, const float* __restrict__ As,
    const bf16_t* __restrict__ Bi, const float* __restrict__ Bs,
    bf16_t* __restrict__ OHi, bf16_t* __restrict__ OLo, float* __restrict__ Of) {
    constexpr int K = 4096, N = 4096;
    __shared__ __align__(16) bf16_t sA[128 * 32];
    __shared__ __align__(16) bf16_t sB[128 * 32];
    __shared__ float sAs[128];
    __shared__ float sBs[128];

    const int tid = threadIdx.x;
    const int bx = blockIdx.x & 31, by = blockIdx.x >> 5;
    const int rowBase = by << 7, colBase = bx << 7;
    const int lane = tid & 63, wave = tid >> 6;
    const int wr = (wave >> 1) << 6, wc = (wave & 1) << 6;
    const int n16 = lane & 15, quad = lane >> 4;

    f32x4 acc[4][4];
#pragma unroll
    for (int m = 0; m < 4; ++m)
#pragma unroll
        for (int n = 0; n < 4; ++n) acc[m][n] = (f32x4){0.f, 0.f, 0.f, 0.f};

    const int ar = tid >> 1, acb = (tid & 1) << 4;   // A stage: 16 i8 per thread
    const int br = tid >> 2, bcb = (tid & 3) << 3;   // B stage: 8 bf16 per issue

    for (int kb = 0; kb < 128; ++kb) {
        const int k0 = kb << 5;
        __syncthreads();
        // ---- stage B (8 KB) via global_load_lds, linear lane order ----
        gl_lds16(&Bi[(long)(colBase + br) * K + k0 + bcb], &sB[(long)tid << 3]);
        gl_lds16(&Bi[(long)(colBase + 64 + br) * K + k0 + bcb], &sB[(long)(256 + tid) << 3]);
        // ---- stage A (4 KB i8 -> 8 KB bf16) ----
        {
            int4 raw = *(const int4*)&Ai[(long)(rowBase + ar) * K + k0 + acb];
            const signed char* pc = (const signed char*)&raw;
            bf16x8 v0, v1;
#pragma unroll
            for (int j = 0; j < 8; ++j) {
                v0[j] = (bf16_t)(float)pc[j];
                v1[j] = (bf16_t)(float)pc[8 + j];
            }
            *(bf16x8*)&sA[(ar << 5) + acb] = v0;
            *(bf16x8*)&sA[(ar << 5) + acb + 8] = v1;
        }
        // ---- stage scales ----
        if (tid < 128) sAs[tid] = As[(long)(rowBase + tid) * 128 + kb];
        else           sBs[tid - 128] = Bs[(long)(colBase + tid - 128) * 128 + kb];
        __syncthreads();

        bf16x8 a[4], b[4];
        f32x4 asv[4];
        float bsv[4];
#pragma unroll
        for (int m = 0; m < 4; ++m) {
            a[m] = *(const bf16x8*)&sA[((wr + (m << 4) + n16) << 5) + (quad << 3)];
            asv[m] = *(const f32x4*)&sAs[wr + (m << 4) + (quad << 2)];
        }
#pragma unroll
        for (int n = 0; n < 4; ++n) {
            b[n] = *(const bf16x8*)&sB[((wc + (n << 4) + n16) << 5) + (quad << 3)];
            bsv[n] = sBs[wc + (n << 4) + n16];
        }
        const f32x4 z = (f32x4){0.f, 0.f, 0.f, 0.f};
#pragma unroll
        for (int m = 0; m < 4; ++m)
#pragma unroll
            for (int n = 0; n < 4; ++n) {
                f32x4 sc = MFMA16(a[m], b[n], z);
                float bn = bsv[n];
#pragma unroll
                for (int r = 0; r < 4; ++r)
                    acc[m][n][r] = fmaf(asv[m][r] * bn, sc[r], acc[m][n][r]);
            }
    }

#pragma unroll
    for (int m = 0; m < 4; ++m)
#pragma unroll
        for (int n = 0; n < 4; ++n) {
            int row = rowBase + wr + (m << 4) + (quad << 2);
            int col = colBase + wc + (n << 4) + n16;
#pragma unroll
            for (int r = 0; r < 4; ++r) {
                if (OSPL) {
                    bf16_t h, l;
                    split_bf16(acc[m][n][r], h, l);
                    OHi[(long)(row + r) * N + col] = h;
                    OLo[(long)(row + r) * N + col] = l;
                } else {
                    Of[(long)(row + r) * N + col] = acc[m][n][r];
                }
            }
        }
}

// ---------------------------------------------------------------------------
// RoPE in place on split q,k.
// ---------------------------------------------------------------------------
__global__ void rope2(bf16_t* __restrict__ qh, bf16_t* __restrict__ ql,
                      bf16_t* __restrict__ kh, bf16_t* __restrict__ kl,
                      const int* __restrict__ pos) {
    int t = blockIdx.x;
    int tid = threadIdx.x;
    __shared__ float cs[64], sn[64];
    if (tid < 64) {
        float invf = (float)pow(10000.0, -(double)tid / 64.0);
        float ang = (float)pos[t] * invf;
        cs[tid] = (float)cos((double)ang);
        sn[tid] = (float)sin((double)ang);
    }
    __syncthreads();
#pragma unroll
    for (int i = 0; i < 8; ++i) {
        int l = i * 256 + tid;
        int hh = l >> 6, d = l & 63;
        long base = (long)t * 4096 + hh * 128 + d;
        float c = cs[d], s = sn[d];
        float a0 = (float)qh[base] + (float)ql[base];
        float a1 = (float)qh[base + 64] + (float)ql[base + 64];
        float r0 = a0 * c - a1 * s, r1 = a1 * c + a0 * s;
        bf16_t x, y;
        split_bf16(r0, x, y); qh[base] = x;      ql[base] = y;
        split_bf16(r1, x, y); qh[base + 64] = x; ql[base + 64] = y;
        float b0 = (float)kh[base] + (float)kl[base];
        float b1 = (float)kh[base + 64] + (float)kl[base + 64];
        r0 = b0 * c - b1 * s; r1 = b1 * c + b0 * s;
        split_bf16(r0, x, y); kh[base] = x;      kl[base] = y;
        split_bf16(r1, x, y); kh[base + 64] = x; kl[base + 64] = y;
    }
}

// ---------------------------------------------------------------------------
// Transpose split V [tok, h*128+d] -> vT[(b*32+h)*128+d][s], both planes.
// ---------------------------------------------------------------------------
__global__ void transpose_vt(const ushort* __restrict__ vh, const ushort* __restrict__ vl,
                             ushort* __restrict__ th, ushort* __restrict__ tl) {
    __shared__ ushort t0[64][68];
    __shared__ ushort t1[64][68];
    int ct = blockIdx.x, tt = blockIdx.y, tid = threadIdx.x;
#pragma unroll
    for (int i = 0; i < 16; ++i) {
        int l = i * 256 + tid, r = l >> 6, c = l & 63;
        long idx = (long)(tt * 64 + r) * 4096 + ct * 64 + c;
        t0[r][c] = vh[idx];
        t1[r][c] = vl[idx];
    }
    __syncthreads();
#pragma unroll
    for (int i = 0; i < 16; ++i) {
        int l = i * 256 + tid, dr = l >> 6, sc = l & 63;
        int colg = ct * 64 + dr, hh = colg >> 7, dl = colg & 127;
        int tok = tt * 64 + sc, b = tok >> 11, s = tok & 2047;
        long o = (long)((b * 32 + hh) * 128 + dl) * 2048 + s;
        th[o] = t0[sc][dr];
        tl[o] = t1[sc][dr];
    }
}

// ---------------------------------------------------------------------------
// Causal flash attention, 2-phase pipelined (unchanged from R4).
// ---------------------------------------------------------------------------
__global__ __launch_bounds__(256, 2) void flash_attn3(
    const bf16_t* __restrict__ qhp, const bf16_t* __restrict__ qlp,
    const bf16_t* __restrict__ khp, const bf16_t* __restrict__ klp,
    const bf16_t* __restrict__ vth, const bf16_t* __restrict__ vtl,
    bf16_t* __restrict__ ohi, bf16_t* __restrict__ olo) {
    __shared__ __align__(16) char smem[75776];

    const int bid = blockIdx.x;
    const int xcd = bid & 7, ixd = bid >> 3;
    const int bh = (xcd << 3) + (ixd >> 4);
    const int qt = 15 - (ixd & 15);
    const int b = bh >> 5, h = bh & 31;
    const int tid = threadIdx.x;
    const int wave = tid >> 6, lane = tid & 63;
    const int n16 = lane & 15, quad = lane >> 4;
    const long tokB = (long)b * 2048;
    const int q0 = qt * 128 + wave * 32;
    const float scale = 0.08838834764831845f;   // 1/sqrt(128)

    bf16_t (*pH)[40] = (bf16_t (*)[40])(smem + 65536 + wave * 2560);
    bf16_t (*pL)[40] = (bf16_t (*)[40])(smem + 65536 + wave * 2560 + 1280);

    bf16x8 qhF[2][4], qlF[2][4];
#pragma unroll
    for (int m = 0; m < 2; ++m) {
        long qoff = (tokB + q0 + m * 16 + n16) * 4096 + h * 128 + quad * 8;
#pragma unroll
        for (int f = 0; f < 4; ++f) {
            qhF[m][f] = *(const bf16x8*)&qhp[qoff + f * 32];
            qlF[m][f] = *(const bf16x8*)&qlp[qoff + f * 32];
        }
    }

    const int kr0 = wave * 8 + quad;
    const int kc0 = ((((lane & 15) << 4) ^ (quad << 4)) >> 1);
    const int kc1 = ((((lane & 15) << 4) ^ ((4 + quad) << 4)) >> 1);
    const int kd0 = kr0 * 256 + ((lane & 15) << 4);
    const int vr0 = wave * 32 + (lane >> 2);
    const int vc0 = ((((lane & 3) << 4) ^ (((lane >> 2) & 3) << 4)) >> 1);
    const int vd0 = vr0 * 64 + ((lane & 3) << 4);
    const long vrow_g = (long)(bh * 128 + vr0) * 2048;

#define STAGE(BUF, KB) do {                                                   \
    char* _bb = smem + ((BUF) << 15);                                         \
    const long _kt = tokB + (long)(KB) * 32;                                  \
    const long _g0 = (_kt + kr0) * 4096 + h * 128;                            \
    gl_lds16(khp + _g0 + kc0,           _bb + kd0);                           \
    gl_lds16(klp + _g0 + kc0,           _bb + 8192 + kd0);                    \
    gl_lds16(khp + _g0 + 4 * 4096 + kc1, _bb + 1024 + kd0);                   \
    gl_lds16(klp + _g0 + 4 * 4096 + kc1, _bb + 8192 + 1024 + kd0);            \
    const long _v0 = vrow_g + (KB) * 32 + vc0;                                \
    gl_lds16(vth + _v0,                 _bb + 16384 + vd0);                   \
    gl_lds16(vtl + _v0,                 _bb + 24576 + vd0);                   \
    gl_lds16(vth + _v0 + 16 * 2048,     _bb + 16384 + 1024 + vd0);            \
    gl_lds16(vtl + _v0 + 16 * 2048,     _bb + 24576 + 1024 + vd0);            \
} while (0)

    f32x4 o[2][8];
#pragma unroll
    for (int m = 0; m < 2; ++m)
#pragma unroll
        for (int dc = 0; dc < 8; ++dc) o[m][dc] = (f32x4){0.f, 0.f, 0.f, 0.f};
    float m_i[2][4], l_i[2][4];
#pragma unroll
    for (int m = 0; m < 2; ++m)
#pragma unroll
        for (int r = 0; r < 4; ++r) { m_i[m][r] = -1e30f; l_i[m][r] = 0.f; }

    const int nkb = 4 * qt + 4;
    const int lastkb = 4 * qt + wave;

    STAGE(0, 0);
    asm volatile("s_waitcnt vmcnt(0)" ::: "memory");
    __builtin_amdgcn_s_barrier();
    asm volatile("" ::: "memory");

    for (int kb = 0; kb < nkb; ++kb) {
        if (kb + 1 < nkb) STAGE((kb + 1) & 1, kb + 1);

        if (kb <= lastkb) {
            const char* bK = smem + ((kb & 1) << 15);
            const char* bV = bK + 16384;

            f32x4 s[2][2];
            const int rswz = (n16 & 7) << 4;
#pragma unroll
            for (int nt = 0; nt < 2; ++nt) {
                const int krow = nt * 16 + n16;
                bf16x8 kh[4], kl[4];
#pragma unroll
                for (int f = 0; f < 4; ++f) {
                    const int cb = ((f << 6) | (quad << 4)) ^ rswz;
                    kh[f] = *(const bf16x8*)(bK + krow * 256 + cb);
                    kl[f] = *(const bf16x8*)(bK + 8192 + krow * 256 + cb);
                }
#pragma unroll
                for (int m = 0; m < 2; ++m) {
                    f32x4 sc = (f32x4){0.f, 0.f, 0.f, 0.f};
#pragma unroll
                    for (int f = 0; f < 4; ++f) {
                        sc = MFMA16(qhF[m][f], kh[f], sc);
                        sc = MFMA16(qhF[m][f], kl[f], sc);
                        sc = MFMA16(qlF[m][f], kh[f], sc);
                    }
                    s[m][nt] = sc;
                }
            }

            if (kb == lastkb) {
                const int key0 = kb * 32 + n16;
#pragma unroll
                for (int m = 0; m < 2; ++m)
#pragma unroll
                    for (int nt = 0; nt < 2; ++nt)
#pragma unroll
                        for (int r = 0; r < 4; ++r) {
                            int qrow = q0 + m * 16 + quad * 4 + r;
                            s[m][nt][r] = (key0 + nt * 16 <= qrow) ? s[m][nt][r] * scale
                                                                   : -1e30f;
                        }
            } else {
#pragma unroll
                for (int m = 0; m < 2; ++m)
#pragma unroll
                    for (int nt = 0; nt < 2; ++nt)
#pragma unroll
                        for (int r = 0; r < 4; ++r) s[m][nt][r] *= scale;
            }

            float alpha[2][4];
#pragma unroll
            for (int m = 0; m < 2; ++m)
#pragma unroll
                for (int r = 0; r < 4; ++r) {
                    float mx = fmaxf(s[m][0][r], s[m][1][r]);
#pragma unroll
                    for (int off = 1; off < 16; off <<= 1) mx = fmaxf(mx, __shfl_xor(mx, off, 64));
                    float mnew = fmaxf(m_i[m][r], mx);
                    alpha[m][r] = expf(m_i[m][r] - mnew);
                    m_i[m][r] = mnew;
                    float p0 = expf(s[m][0][r] - mnew);
                    float p1 = expf(s[m][1][r] - mnew);
                    s[m][0][r] = p0;
                    s[m][1][r] = p1;
                    float sum = p0 + p1;
#pragma unroll
                    for (int off = 1; off < 16; off <<= 1) sum += __shfl_xor(sum, off, 64);
                    l_i[m][r] = l_i[m][r] * alpha[m][r] + sum;
                }

            bf16x8 ph2[2], pl2[2];
#pragma unroll
            for (int m = 0; m < 2; ++m) {
#pragma unroll
                for (int nt = 0; nt < 2; ++nt)
#pragma unroll
                    for (int r = 0; r < 4; ++r) {
                        bf16_t hh2, ll2;
                        split_bf16(s[m][nt][r], hh2, ll2);
                        pH[quad * 4 + r][nt * 16 + n16] = hh2;
                        pL[quad * 4 + r][nt * 16 + n16] = ll2;
                    }
                ph2[m] = *(const bf16x8*)&pH[n16][quad * 8];
                pl2[m] = *(const bf16x8*)&pL[n16][quad * 8];
            }

#pragma unroll
            for (int dc = 0; dc < 8; ++dc) {
                const int vrow = dc * 16 + n16;
                const int vcb = ((quad ^ (n16 & 3)) << 4);
                bf16x8 vh = *(const bf16x8*)(bV + vrow * 64 + vcb);
                bf16x8 vl = *(const bf16x8*)(bV + 8192 + vrow * 64 + vcb);
#pragma unroll
                for (int m = 0; m < 2; ++m) {
#pragma unroll
                    for (int r = 0; r < 4; ++r) o[m][dc][r] *= alpha[m][r];
                    o[m][dc] = MFMA16(ph2[m], vh, o[m][dc]);
                    o[m][dc] = MFMA16(ph2[m], vl, o[m][dc]);
                    o[m][dc] = MFMA16(pl2[m], vh, o[m][dc]);
                }
            }
        }

        asm volatile("s_waitcnt vmcnt(0)" ::: "memory");
        __builtin_amdgcn_s_barrier();
        asm volatile("" ::: "memory");
    }
#undef STAGE

#pragma unroll
    for (int m = 0; m < 2; ++m)
#pragma unroll
        for (int r = 0; r < 4; ++r) {
            float invl = 1.0f / l_i[m][r];
            long row = tokB + q0 + m * 16 + quad * 4 + r;
#pragma unroll
            for (int dc = 0; dc < 8; ++dc) {
                bf16_t hh2, ll2;
                split_bf16(o[m][dc][r] * invl, hh2, ll2);
                ohi[row * 4096 + h * 128 + dc * 16 + n16] = hh2;
                olo[row * 4096 + h * 128 + dc * 16 + n16] = ll2;
            }
        }
}

// ---------------------------------------------------------------------------
// Launcher.  ws (192 MB guaranteed):
//   ws[  0.. 64) q-split (hi/lo)
//   ws[ 64..128) k-split (hi/lo)
//   ws[128..192) scratch S:
//     qlinear phases: Xi i8 @S+0 (16M), Xs @S+16M (2M),
//                     Wi bf16 @S+18M (32M), Wsc @S+50M (2M)
//     attention phase: vT-split @S+0 (64M)
//   d_out: v-split -> attn-split -> final fp32
// ---------------------------------------------------------------------------
extern "C" void kernel_launch(void* const* d_in, const int* in_sizes, int n_in,
                              void* d_out, int out_size, void* d_ws, size_t ws_size,
                              hipStream_t stream) {
    const float* x  = (const float*)d_in[0];
    const float* Wq = (const float*)d_in[1];
    const float* Wk = (const float*)d_in[2];
    const float* Wv = (const float*)d_in[3];
    const float* Wo = (const float*)d_in[4];
    const int* pos  = (const int*)d_in[5];
    const int* rid  = (const int*)d_in[6];

    const size_t MB = 1024ull * 1024ull;
    char* ws = (char*)d_ws;
    bf16_t* QH = (bf16_t*)(ws);
    bf16_t* QL = (bf16_t*)(ws + 32 * MB);
    bf16_t* KH = (bf16_t*)(ws + 64 * MB);
    bf16_t* KL = (bf16_t*)(ws + 96 * MB);
    char* S = ws + 128 * MB;
    signed char* Xi = (signed char*)S;            // 16 MB
    float*  Xs  = (float*)(S + 16 * MB);          // 2 MB
    bf16_t* Wi  = (bf16_t*)(S + 18 * MB);         // 32 MB
    float*  Wsc = (float*)(S + 50 * MB);          // 2 MB
    bf16_t* VTh = (bf16_t*)S;                     // 32 MB (after QKV phase)
    bf16_t* VTl = (bf16_t*)(S + 32 * MB);         // 32 MB
    bf16_t* OUh = (bf16_t*)d_out;
    bf16_t* OUl = (bf16_t*)((char*)d_out + 32 * MB);

    const int QG = 65536;

    // ---- quantize x once (i8 + scales) ----
    quant_is<1><<<QG, 256, 0, stream>>>(x, nullptr, nullptr, rid, 0, 1, Xi, nullptr, Xs);

    // ---- q = xq @ Wq^T ----
    quant_is<0><<<QG, 256, 0, stream>>>(Wq, nullptr, nullptr, rid, 0, 0, nullptr, Wi, Wsc);
    gemm_is<1><<<1024, 256, 0, stream>>>(Xi, Xs, Wi, Wsc, QH, QL, nullptr);
    // ---- k ----
    quant_is<0><<<QG, 256, 0, stream>>>(Wk, nullptr, nullptr, rid, 0, 0, nullptr, Wi, Wsc);
    gemm_is<1><<<1024, 256, 0, stream>>>(Xi, Xs, Wi, Wsc, KH, KL, nullptr);
    // ---- v (into d_out scratch) ----
    quant_is<0><<<QG, 256, 0, stream>>>(Wv, nullptr, nullptr, rid, 0, 0, nullptr, Wi, Wsc);
    gemm_is<1><<<1024, 256, 0, stream>>>(Xi, Xs, Wi, Wsc, OUh, OUl, nullptr);

    rope2<<<4096, 256, 0, stream>>>(QH, QL, KH, KL, pos);

    transpose_vt<<<dim3(64, 64), 256, 0, stream>>>((const ushort*)OUh, (const ushort*)OUl,
                                                   (ushort*)VTh, (ushort*)VTl);

    flash_attn3<<<1024, 256, 0, stream>>>(QH, QL, KH, KL, VTh, VTl, OUh, OUl);

    // ---- out = attnq @ Wo^T (writes fp32 directly into d_out) ----
    quant_is<1><<<QG, 256, 0, stream>>>(nullptr, OUh, OUl, rid, 1, 1, Xi, nullptr, Xs);
    quant_is<0><<<QG, 256, 0, stream>>>(Wo, nullptr, nullptr, rid, 0, 0, nullptr, Wi, Wsc);
    gemm_is<0><<<1024, 256, 0, stream>>>(Xi, Xs, Wi, Wsc, nullptr, nullptr, (float*)d_out);

    (void)in_sizes; (void)n_in; (void)out_size; (void)ws_size;
}

// Round 3
// 2381.112 us; speedup vs baseline: 1.2641x; 1.0636x over previous
//
#include <hip/hip_runtime.h>

// ---------------------------------------------------------------------------
// QLlamaAttention: mixed 4/6/8-bit block fake-quant qlinear (q,k,v,o) + RoPE +
// causal SDPA.
//
// R5 -> R6: GEMM gets the same 2-phase pipeline that fixed flash in R4:
//   - double-buffered LDS tiles (34 KB), stage(next) issued BEFORE compute,
//     one raw s_barrier + counted vmcnt per K-step (was __syncthreads drain
//     with full latency exposure every step)
//   - B (weight bf16 codes) + scales staged via global_load_lds (async DMA);
//     A (activation i8 codes) T14 reg-staged (issue early, cvt+write late)
//   - scale arrays transposed to [kb][row] -> coalesced 256 B/wave loads
//     (was 512 B-strided, 128 cache lines per step)
//   - XCD-column block swizzle: each XCD owns 4 B-panels (4 MB, L2-resident)
//   - quant_is vectorized x4
// Exact-int math unchanged: codes are integers (exact in bf16/i8), one MFMA
// per 32-block is exact in fp32, scales applied per block via VALU FMA.
// ---------------------------------------------------------------------------

typedef __bf16 bf16_t;
typedef __bf16 bf16x4 __attribute__((ext_vector_type(4)));
typedef __bf16 bf16x8 __attribute__((ext_vector_type(8)));
typedef float f32x4 __attribute__((ext_vector_type(4)));

#define MFMA16(a, b, c) __builtin_amdgcn_mfma_f32_16x16x32_bf16(a, b, c, 0, 0, 0)

__device__ __forceinline__ void split_bf16(float x, bf16_t& h, bf16_t& l) {
    h = (bf16_t)x;
    l = (bf16_t)(x - (float)h);
}

typedef const __attribute__((address_space(1))) void glb_v;
typedef __attribute__((address_space(3))) void lds_v;

__device__ __forceinline__ void gl_lds16(const void* g, void* l) {
    __builtin_amdgcn_global_load_lds((glb_v*)g, (lds_v*)l, 16, 0, 0);
}
__device__ __forceinline__ void gl_lds4(const void* g, void* l) {
    __builtin_amdgcn_global_load_lds((glb_v*)g, (lds_v*)l, 4, 0, 0);
}

// ---------------------------------------------------------------------------
// Mixed block fake-quant of a [4096 x 4096] matrix -> integer codes + scales.
// 4 elements/thread.  OUT_I8=1: i8 codes (activations); 0: bf16 codes
// (weights).  Scales transposed: qsT[kb][row], kb = col/32.
// ---------------------------------------------------------------------------
template<int OUT_I8>
__global__ void quant_is(const float* __restrict__ srcf,
                         const bf16_t* __restrict__ shi, const bf16_t* __restrict__ slo,
                         const int* __restrict__ rid, int src_split, int gather,
                         signed char* __restrict__ qi8, bf16_t* __restrict__ qbf,
                         float* __restrict__ qsT) {
    long idx = ((long)blockIdx.x * 256 + threadIdx.x) << 2;
    int col = (int)(idx & 4095);
    long rowoff = idx & ~4095L;     // row * 4096
    float v[4];
    float a = 0.f;
#pragma unroll
    for (int j = 0; j < 4; ++j) {
        int g = gather ? rid[col + j] : col + j;
        float x = src_split ? ((float)shi[rowoff + g] + (float)slo[rowoff + g])
                            : srcf[rowoff + g];
        v[j] = x;
        a = fmaxf(a, fabsf(x));
    }
    // 8 consecutive lanes cover one 32-elem block
#pragma unroll
    for (int off = 1; off < 8; off <<= 1) a = fmaxf(a, __shfl_xor(a, off, 64));
    float qmax = (col < 2560) ? 7.0f : (col < 3584 ? 31.0f : 127.0f);
    float scale = fmaxf(a / qmax, 1e-8f);
    float inv = 1.0f / scale;
    if (OUT_I8) {
        int pk = 0;
#pragma unroll
        for (int j = 0; j < 4; ++j) {
            float q = fminf(fmaxf(rintf(v[j] * inv), -qmax), qmax);
            pk |= (int)(unsigned char)(signed char)(int)q << (8 * j);
        }
        *(int*)&qi8[idx] = pk;
    } else {
        bf16x4 pk;
#pragma unroll
        for (int j = 0; j < 4; ++j) {
            float q = fminf(fmaxf(rintf(v[j] * inv), -qmax), qmax);
            pk[j] = (bf16_t)q;
        }
        *(bf16x4*)&qbf[idx] = pk;
    }
    if ((col & 31) == 0) qsT[((long)(col >> 5) << 12) + (idx >> 12)] = scale;
}

// ---------------------------------------------------------------------------
// GEMM C[4096,4096] = (As.Aq) * (Bs.Bq)^T, exact-int inner blocks,
// 2-phase pipelined.  128x128 tile, BK=32 (= one scale block).
//   A: i8 codes, T14 reg-staged (int4 load early, cvt+ds_write late)
//   B: bf16 codes via global_load_lds;  scales [kb][row] via global_load_lds
// Per K-step: ISSUE(next) -> compute(cur) -> vmcnt(0), cvt+write A,
// lgkmcnt(0), s_barrier.
// ---------------------------------------------------------------------------
template<int OSPL>
__global__ __launch_bounds__(256, 2) void gemm_is(
    const signed char* __restrict__ Ai, const float* __restrict__ AsT,
    const bf16_t* __restrict__ Bi, const float* __restrict__ BsT,
    bf16_t* __restrict__ OHi, bf16_t* __restrict__ OLo, float* __restrict__ Of) {
    constexpr int K = 4096, N = 4096;
    __shared__ __align__(16) bf16_t sA[2][128 * 32];   // 8 KB / buf
    __shared__ __align__(16) bf16_t sB[2][128 * 32];   // 8 KB / buf
    __shared__ __align__(16) float  sS[2][256];        // [0,128) A, [128,256) B

    const int tid = threadIdx.x;
    // XCD-column swizzle: xcd owns 4 bx columns (B-panels L2-resident)
    const int bid = blockIdx.x;
    const int xcd = bid & 7, j = bid >> 3;
    const int bx = xcd * 4 + (j & 3), by = j >> 2;
    const int rowBase = by << 7, colBase = bx << 7;
    const int lane = tid & 63, wave = tid >> 6;
    const int wr = (wave >> 1) << 6, wc = (wave & 1) << 6;
    const int n16 = lane & 15, quad = lane >> 4;

    // ---- staging geometry ----
    const int arow = tid >> 1, achk = (tid & 1) << 4;          // 16 i8 per thread
    const long aSrc = (long)(rowBase + arow) * K + achk;       // + k0
    const int aDst = arow * 64 + achk * 2;                     // bytes in sA plane
    const int brow = tid >> 2, bchk = (tid & 3) << 3;          // 8 bf16 per issue
    const long bSrc0 = (long)(colBase + brow) * K + bchk;
    const long bSrc1 = (long)(colBase + 64 + brow) * K + bchk;
    const int bDst = tid << 4;                                 // bytes; issue1 +4096
    const int sIsB = wave >> 1;
    const float* sPtr = (sIsB ? BsT + colBase : AsT + rowBase) + ((wave & 1) << 6) + lane;
    const int sDst = (sIsB ? 512 : 0) + ((wave & 1) << 8) + (lane << 2);

    f32x4 acc[4][4];
#pragma unroll
    for (int m = 0; m < 4; ++m)
#pragma unroll
        for (int n = 0; n < 4; ++n) acc[m][n] = (f32x4){0.f, 0.f, 0.f, 0.f};

    int4 aReg;

#define ISSUE(BUF, KB) do {                                                   \
    char* _b = (char*)sB[BUF]; char* _s = (char*)sS[BUF];                     \
    const int _k0 = (KB) << 5;                                                \
    gl_lds16(Bi + bSrc0 + _k0, _b + bDst);                                    \
    gl_lds16(Bi + bSrc1 + _k0, _b + 4096 + bDst);                             \
    gl_lds4(sPtr + ((long)(KB) << 12), _s + sDst);                            \
    aReg = *(const int4*)(Ai + aSrc + _k0);                                   \
} while (0)

#define FINISH(BUF) do {                                                      \
    asm volatile("s_waitcnt vmcnt(0)" ::: "memory");                          \
    const signed char* _pc = (const signed char*)&aReg;                       \
    bf16x8 _v0, _v1;                                                          \
    _Pragma("unroll")                                                         \
    for (int _j = 0; _j < 8; ++_j) {                                          \
        _v0[_j] = (bf16_t)(float)_pc[_j];                                     \
        _v1[_j] = (bf16_t)(float)_pc[8 + _j];                                 \
    }                                                                         \
    *(bf16x8*)((char*)sA[BUF] + aDst) = _v0;                                  \
    *(bf16x8*)((char*)sA[BUF] + aDst + 16) = _v1;                             \
    asm volatile("s_waitcnt lgkmcnt(0)" ::: "memory");                        \
    __builtin_amdgcn_s_barrier();                                             \
    asm volatile("" ::: "memory");                                            \
} while (0)

    ISSUE(0, 0);
    FINISH(0);

    for (int kb = 0; kb < 128; ++kb) {
        const int cur = kb & 1;
        if (kb < 127) ISSUE(cur ^ 1, kb + 1);

        const char* pA = (const char*)sA[cur];
        const char* pB = (const char*)sB[cur];
        const char* pS = (const char*)sS[cur];
        bf16x8 a[4], b[4];
        f32x4 asv[4];
        float bsv[4];
#pragma unroll
        for (int m = 0; m < 4; ++m) {
            a[m] = *(const bf16x8*)(pA + (wr + (m << 4) + n16) * 64 + (quad << 4));
            asv[m] = *(const f32x4*)(pS + ((wr + (m << 4) + (quad << 2)) << 2));
        }
#pragma unroll
        for (int n = 0; n < 4; ++n) {
            b[n] = *(const bf16x8*)(pB + (wc + (n << 4) + n16) * 64 + (quad << 4));
            bsv[n] = *(const float*)(pS + 512 + ((wc + (n << 4) + n16) << 2));
        }
        const f32x4 z = (f32x4){0.f, 0.f, 0.f, 0.f};
#pragma unroll
        for (int m = 0; m < 4; ++m)
#pragma unroll
            for (int n = 0; n < 4; ++n) {
                f32x4 sc = MFMA16(a[m], b[n], z);
                float bn = bsv[n];
#pragma unroll
                for (int r = 0; r < 4; ++r)
                    acc[m][n][r] = fmaf(asv[m][r] * bn, sc[r], acc[m][n][r]);
            }

        if (kb < 127) FINISH(cur ^ 1);
    }
#undef ISSUE
#undef FINISH

#pragma unroll
    for (int m = 0; m < 4; ++m)
#pragma unroll
        for (int n = 0; n < 4; ++n) {
            int row = rowBase + wr + (m << 4) + (quad << 2);
            int col = colBase + wc + (n << 4) + n16;
#pragma unroll
            for (int r = 0; r < 4; ++r) {
                if (OSPL) {
                    bf16_t h, l;
                    split_bf16(acc[m][n][r], h, l);
                    OHi[(long)(row + r) * N + col] = h;
                    OLo[(long)(row + r) * N + col] = l;
                } else {
                    Of[(long)(row + r) * N + col] = acc[m][n][r];
                }
            }
        }
}

// ---------------------------------------------------------------------------
// RoPE in place on split q,k.
// ---------------------------------------------------------------------------
__global__ void rope2(bf16_t* __restrict__ qh, bf16_t* __restrict__ ql,
                      bf16_t* __restrict__ kh, bf16_t* __restrict__ kl,
                      const int* __restrict__ pos) {
    int t = blockIdx.x;
    int tid = threadIdx.x;
    __shared__ float cs[64], sn[64];
    if (tid < 64) {
        float invf = (float)pow(10000.0, -(double)tid / 64.0);
        float ang = (float)pos[t] * invf;
        cs[tid] = (float)cos((double)ang);
        sn[tid] = (float)sin((double)ang);
    }
    __syncthreads();
#pragma unroll
    for (int i = 0; i < 8; ++i) {
        int l = i * 256 + tid;
        int hh = l >> 6, d = l & 63;
        long base = (long)t * 4096 + hh * 128 + d;
        float c = cs[d], s = sn[d];
        float a0 = (float)qh[base] + (float)ql[base];
        float a1 = (float)qh[base + 64] + (float)ql[base + 64];
        float r0 = a0 * c - a1 * s, r1 = a1 * c + a0 * s;
        bf16_t x, y;
        split_bf16(r0, x, y); qh[base] = x;      ql[base] = y;
        split_bf16(r1, x, y); qh[base + 64] = x; ql[base + 64] = y;
        float b0 = (float)kh[base] + (float)kl[base];
        float b1 = (float)kh[base + 64] + (float)kl[base + 64];
        r0 = b0 * c - b1 * s; r1 = b1 * c + b0 * s;
        split_bf16(r0, x, y); kh[base] = x;      kl[base] = y;
        split_bf16(r1, x, y); kh[base + 64] = x; kl[base + 64] = y;
    }
}

// ---------------------------------------------------------------------------
// Transpose split V [tok, h*128+d] -> vT[(b*32+h)*128+d][s], both planes.
// ---------------------------------------------------------------------------
__global__ void transpose_vt(const ushort* __restrict__ vh, const ushort* __restrict__ vl,
                             ushort* __restrict__ th, ushort* __restrict__ tl) {
    __shared__ ushort t0[64][68];
    __shared__ ushort t1[64][68];
    int ct = blockIdx.x, tt = blockIdx.y, tid = threadIdx.x;
#pragma unroll
    for (int i = 0; i < 16; ++i) {
        int l = i * 256 + tid, r = l >> 6, c = l & 63;
        long idx = (long)(tt * 64 + r) * 4096 + ct * 64 + c;
        t0[r][c] = vh[idx];
        t1[r][c] = vl[idx];
    }
    __syncthreads();
#pragma unroll
    for (int i = 0; i < 16; ++i) {
        int l = i * 256 + tid, dr = l >> 6, sc = l & 63;
        int colg = ct * 64 + dr, hh = colg >> 7, dl = colg & 127;
        int tok = tt * 64 + sc, b = tok >> 11, s = tok & 2047;
        long o = (long)((b * 32 + hh) * 128 + dl) * 2048 + s;
        th[o] = t0[sc][dr];
        tl[o] = t1[sc][dr];
    }
}

// ---------------------------------------------------------------------------
// Causal flash attention, 2-phase pipelined (unchanged from R4/R5).
// ---------------------------------------------------------------------------
__global__ __launch_bounds__(256, 2) void flash_attn3(
    const bf16_t* __restrict__ qhp, const bf16_t* __restrict__ qlp,
    const bf16_t* __restrict__ khp, const bf16_t* __restrict__ klp,
    const bf16_t* __restrict__ vth, const bf16_t* __restrict__ vtl,
    bf16_t* __restrict__ ohi, bf16_t* __restrict__ olo) {
    __shared__ __align__(16) char smem[75776];

    const int bid = blockIdx.x;
    const int xcd = bid & 7, ixd = bid >> 3;
    const int bh = (xcd << 3) + (ixd >> 4);
    const int qt = 15 - (ixd & 15);
    const int b = bh >> 5, h = bh & 31;
    const int tid = threadIdx.x;
    const int wave = tid >> 6, lane = tid & 63;
    const int n16 = lane & 15, quad = lane >> 4;
    const long tokB = (long)b * 2048;
    const int q0 = qt * 128 + wave * 32;
    const float scale = 0.08838834764831845f;   // 1/sqrt(128)

    bf16_t (*pH)[40] = (bf16_t (*)[40])(smem + 65536 + wave * 2560);
    bf16_t (*pL)[40] = (bf16_t (*)[40])(smem + 65536 + wave * 2560 + 1280);

    bf16x8 qhF[2][4], qlF[2][4];
#pragma unroll
    for (int m = 0; m < 2; ++m) {
        long qoff = (tokB + q0 + m * 16 + n16) * 4096 + h * 128 + quad * 8;
#pragma unroll
        for (int f = 0; f < 4; ++f) {
            qhF[m][f] = *(const bf16x8*)&qhp[qoff + f * 32];
            qlF[m][f] = *(const bf16x8*)&qlp[qoff + f * 32];
        }
    }

    const int kr0 = wave * 8 + quad;
    const int kc0 = ((((lane & 15) << 4) ^ (quad << 4)) >> 1);
    const int kc1 = ((((lane & 15) << 4) ^ ((4 + quad) << 4)) >> 1);
    const int kd0 = kr0 * 256 + ((lane & 15) << 4);
    const int vr0 = wave * 32 + (lane >> 2);
    const int vc0 = ((((lane & 3) << 4) ^ (((lane >> 2) & 3) << 4)) >> 1);
    const int vd0 = vr0 * 64 + ((lane & 3) << 4);
    const long vrow_g = (long)(bh * 128 + vr0) * 2048;

#define STAGE(BUF, KB) do {                                                   \
    char* _bb = smem + ((BUF) << 15);                                         \
    const long _kt = tokB + (long)(KB) * 32;                                  \
    const long _g0 = (_kt + kr0) * 4096 + h * 128;                            \
    gl_lds16(khp + _g0 + kc0,           _bb + kd0);                           \
    gl_lds16(klp + _g0 + kc0,           _bb + 8192 + kd0);                    \
    gl_lds16(khp + _g0 + 4 * 4096 + kc1, _bb + 1024 + kd0);                   \
    gl_lds16(klp + _g0 + 4 * 4096 + kc1, _bb + 8192 + 1024 + kd0);            \
    const long _v0 = vrow_g + (KB) * 32 + vc0;                                \
    gl_lds16(vth + _v0,                 _bb + 16384 + vd0);                   \
    gl_lds16(vtl + _v0,                 _bb + 24576 + vd0);                   \
    gl_lds16(vth + _v0 + 16 * 2048,     _bb + 16384 + 1024 + vd0);            \
    gl_lds16(vtl + _v0 + 16 * 2048,     _bb + 24576 + 1024 + vd0);            \
} while (0)

    f32x4 o[2][8];
#pragma unroll
    for (int m = 0; m < 2; ++m)
#pragma unroll
        for (int dc = 0; dc < 8; ++dc) o[m][dc] = (f32x4){0.f, 0.f, 0.f, 0.f};
    float m_i[2][4], l_i[2][4];
#pragma unroll
    for (int m = 0; m < 2; ++m)
#pragma unroll
        for (int r = 0; r < 4; ++r) { m_i[m][r] = -1e30f; l_i[m][r] = 0.f; }

    const int nkb = 4 * qt + 4;
    const int lastkb = 4 * qt + wave;

    STAGE(0, 0);
    asm volatile("s_waitcnt vmcnt(0)" ::: "memory");
    __builtin_amdgcn_s_barrier();
    asm volatile("" ::: "memory");

    for (int kb = 0; kb < nkb; ++kb) {
        if (kb + 1 < nkb) STAGE((kb + 1) & 1, kb + 1);

        if (kb <= lastkb) {
            const char* bK = smem + ((kb & 1) << 15);
            const char* bV = bK + 16384;

            f32x4 s[2][2];
            const int rswz = (n16 & 7) << 4;
#pragma unroll
            for (int nt = 0; nt < 2; ++nt) {
                const int krow = nt * 16 + n16;
                bf16x8 kh[4], kl[4];
#pragma unroll
                for (int f = 0; f < 4; ++f) {
                    const int cb = ((f << 6) | (quad << 4)) ^ rswz;
                    kh[f] = *(const bf16x8*)(bK + krow * 256 + cb);
                    kl[f] = *(const bf16x8*)(bK + 8192 + krow * 256 + cb);
                }
#pragma unroll
                for (int m = 0; m < 2; ++m) {
                    f32x4 sc = (f32x4){0.f, 0.f, 0.f, 0.f};
#pragma unroll
                    for (int f = 0; f < 4; ++f) {
                        sc = MFMA16(qhF[m][f], kh[f], sc);
                        sc = MFMA16(qhF[m][f], kl[f], sc);
                        sc = MFMA16(qlF[m][f], kh[f], sc);
                    }
                    s[m][nt] = sc;
                }
            }

            if (kb == lastkb) {
                const int key0 = kb * 32 + n16;
#pragma unroll
                for (int m = 0; m < 2; ++m)
#pragma unroll
                    for (int nt = 0; nt < 2; ++nt)
#pragma unroll
                        for (int r = 0; r < 4; ++r) {
                            int qrow = q0 + m * 16 + quad * 4 + r;
                            s[m][nt][r] = (key0 + nt * 16 <= qrow) ? s[m][nt][r] * scale
                                                                   : -1e30f;
                        }
            } else {
#pragma unroll
                for (int m = 0; m < 2; ++m)
#pragma unroll
                    for (int nt = 0; nt < 2; ++nt)
#pragma unroll
                        for (int r = 0; r < 4; ++r) s[m][nt][r] *= scale;
            }

            float alpha[2][4];
#pragma unroll
            for (int m = 0; m < 2; ++m)
#pragma unroll
                for (int r = 0; r < 4; ++r) {
                    float mx = fmaxf(s[m][0][r], s[m][1][r]);
#pragma unroll
                    for (int off = 1; off < 16; off <<= 1) mx = fmaxf(mx, __shfl_xor(mx, off, 64));
                    float mnew = fmaxf(m_i[m][r], mx);
                    alpha[m][r] = expf(m_i[m][r] - mnew);
                    m_i[m][r] = mnew;
                    float p0 = expf(s[m][0][r] - mnew);
                    float p1 = expf(s[m][1][r] - mnew);
                    s[m][0][r] = p0;
                    s[m][1][r] = p1;
                    float sum = p0 + p1;
#pragma unroll
                    for (int off = 1; off < 16; off <<= 1) sum += __shfl_xor(sum, off, 64);
                    l_i[m][r] = l_i[m][r] * alpha[m][r] + sum;
                }

            bf16x8 ph2[2], pl2[2];
#pragma unroll
            for (int m = 0; m < 2; ++m) {
#pragma unroll
                for (int nt = 0; nt < 2; ++nt)
#pragma unroll
                    for (int r = 0; r < 4; ++r) {
                        bf16_t hh2, ll2;
                        split_bf16(s[m][nt][r], hh2, ll2);
                        pH[quad * 4 + r][nt * 16 + n16] = hh2;
                        pL[quad * 4 + r][nt * 16 + n16] = ll2;
                    }
                ph2[m] = *(const bf16x8*)&pH[n16][quad * 8];
                pl2[m] = *(const bf16x8*)&pL[n16][quad * 8];
            }

#pragma unroll
            for (int dc = 0; dc < 8; ++dc) {
                const int vrow = dc * 16 + n16;
                const int vcb = ((quad ^ (n16 & 3)) << 4);
                bf16x8 vh = *(const bf16x8*)(bV + vrow * 64 + vcb);
                bf16x8 vl = *(const bf16x8*)(bV + 8192 + vrow * 64 + vcb);
#pragma unroll
                for (int m = 0; m < 2; ++m) {
#pragma unroll
                    for (int r = 0; r < 4; ++r) o[m][dc][r] *= alpha[m][r];
                    o[m][dc] = MFMA16(ph2[m], vh, o[m][dc]);
                    o[m][dc] = MFMA16(ph2[m], vl, o[m][dc]);
                    o[m][dc] = MFMA16(pl2[m], vh, o[m][dc]);
                }
            }
        }

        asm volatile("s_waitcnt vmcnt(0)" ::: "memory");
        __builtin_amdgcn_s_barrier();
        asm volatile("" ::: "memory");
    }
#undef STAGE

#pragma unroll
    for (int m = 0; m < 2; ++m)
#pragma unroll
        for (int r = 0; r < 4; ++r) {
            float invl = 1.0f / l_i[m][r];
            long row = tokB + q0 + m * 16 + quad * 4 + r;
#pragma unroll
            for (int dc = 0; dc < 8; ++dc) {
                bf16_t hh2, ll2;
                split_bf16(o[m][dc][r] * invl, hh2, ll2);
                ohi[row * 4096 + h * 128 + dc * 16 + n16] = hh2;
                olo[row * 4096 + h * 128 + dc * 16 + n16] = ll2;
            }
        }
}

// ---------------------------------------------------------------------------
// Launcher.  ws (192 MB):
//   [  0.. 32) QH   [ 32.. 64) QL   [ 64.. 96) KH   [ 96..128) KL
//   phase 1 (QKV): Xi i8 @128..144, XsT @144..146, WsT @146..148,
//                  Wi bf16 @160..192;  v-split -> d_out
//   phase 2: VT @128..192 (VTh@128, VTl@160); flash -> d_out (attn split)
//   phase 3 (Wo): Xi2 i8 @64..80 (K dead), Xs2T @96..98,
//                 Wo bf16 @128..160, WoST @160..162; gemm -> d_out fp32
// ---------------------------------------------------------------------------
extern "C" void kernel_launch(void* const* d_in, const int* in_sizes, int n_in,
                              void* d_out, int out_size, void* d_ws, size_t ws_size,
                              hipStream_t stream) {
    const float* x  = (const float*)d_in[0];
    const float* Wq = (const float*)d_in[1];
    const float* Wk = (const float*)d_in[2];
    const float* Wv = (const float*)d_in[3];
    const float* Wo = (const float*)d_in[4];
    const int* pos  = (const int*)d_in[5];
    const int* rid  = (const int*)d_in[6];

    const size_t MB = 1024ull * 1024ull;
    char* ws = (char*)d_ws;
    bf16_t* QH = (bf16_t*)(ws);
    bf16_t* QL = (bf16_t*)(ws + 32 * MB);
    bf16_t* KH = (bf16_t*)(ws + 64 * MB);
    bf16_t* KL = (bf16_t*)(ws + 96 * MB);
    // phase 1
    signed char* Xi = (signed char*)(ws + 128 * MB);  // 16 MB
    float*  XsT = (float*)(ws + 144 * MB);            // 2 MB
    float*  WsT = (float*)(ws + 146 * MB);            // 2 MB
    bf16_t* Wi  = (bf16_t*)(ws + 160 * MB);           // 32 MB
    // phase 2
    bf16_t* VTh = (bf16_t*)(ws + 128 * MB);
    bf16_t* VTl = (bf16_t*)(ws + 160 * MB);
    // phase 3
    signed char* Xi2 = (signed char*)(ws + 64 * MB);  // 16 MB (KH dead)
    float*  Xs2T = (float*)(ws + 96 * MB);            // 2 MB (KL dead)
    bf16_t* Wo_i = (bf16_t*)(ws + 128 * MB);          // 32 MB (VT dead)
    float*  WoST = (float*)(ws + 160 * MB);           // 2 MB
    bf16_t* OUh = (bf16_t*)d_out;
    bf16_t* OUl = (bf16_t*)((char*)d_out + 32 * MB);

    const int QG = 16384;

    // ---- quantize x once (i8 + transposed scales) ----
    quant_is<1><<<QG, 256, 0, stream>>>(x, nullptr, nullptr, rid, 0, 1, Xi, nullptr, XsT);

    // ---- q = xq @ Wq^T ----
    quant_is<0><<<QG, 256, 0, stream>>>(Wq, nullptr, nullptr, rid, 0, 0, nullptr, Wi, WsT);
    gemm_is<1><<<1024, 256, 0, stream>>>(Xi, XsT, Wi, WsT, QH, QL, nullptr);
    // ---- k ----
    quant_is<0><<<QG, 256, 0, stream>>>(Wk, nullptr, nullptr, rid, 0, 0, nullptr, Wi, WsT);
    gemm_is<1><<<1024, 256, 0, stream>>>(Xi, XsT, Wi, WsT, KH, KL, nullptr);
    // ---- v (into d_out scratch) ----
    quant_is<0><<<QG, 256, 0, stream>>>(Wv, nullptr, nullptr, rid, 0, 0, nullptr, Wi, WsT);
    gemm_is<1><<<1024, 256, 0, stream>>>(Xi, XsT, Wi, WsT, OUh, OUl, nullptr);

    rope2<<<4096, 256, 0, stream>>>(QH, QL, KH, KL, pos);

    transpose_vt<<<dim3(64, 64), 256, 0, stream>>>((const ushort*)OUh, (const ushort*)OUl,
                                                   (ushort*)VTh, (ushort*)VTl);

    flash_attn3<<<1024, 256, 0, stream>>>(QH, QL, KH, KL, VTh, VTl, OUh, OUl);

    // ---- out = attnq @ Wo^T (fp32 direct into d_out) ----
    quant_is<1><<<QG, 256, 0, stream>>>(nullptr, OUh, OUl, rid, 1, 1, Xi2, nullptr, Xs2T);
    quant_is<0><<<QG, 256, 0, stream>>>(Wo, nullptr, nullptr, rid, 0, 0, nullptr, Wo_i, WoST);
    gemm_is<0><<<1024, 256, 0, stream>>>(Xi2, Xs2T, Wo_i, WoST, nullptr, nullptr, (float*)d_out);

    (void)in_sizes; (void)n_in; (void)out_size; (void)ws_size;
}

// Round 4
// 2185.595 us; speedup vs baseline: 1.3772x; 1.0895x over previous
//
#include <hip/hip_runtime.h>

// ---------------------------------------------------------------------------
// QLlamaAttention: mixed 4/6/8-bit block fake-quant qlinear (q,k,v,o) + RoPE +
// causal SDPA.
//
// R6 -> R7:
//   - gemm_is: LDS XOR-swizzle (chunk ^= (row&3)<<4) on A and B tiles --
//     the [128][32]bf16 64-B rows made every fragment ds_read_b128 ~4-8-way
//     bank-conflicted (the real R0..R6 GEMM bottleneck).  B's swizzle is done
//     by pre-swizzling the global_load_lds SOURCE chunk (linear LDS dest);
//     A's by swizzling the manual ds_write dest.  Reads apply the same XOR.
//   - gemm_is: depth-2 pipeline, 3 LDS buffer sets, counted s_waitcnt
//     vmcnt(4) (never 0 in steady state) -- one full K-step of latency slack.
//   - transpose_vt: uint4 global I/O both sides + swizzled LDS (was scalar
//     2B loads/stores).
//   - quant_is: templated; float4 fast path for the 4 weight quants.
//   - rope2: x8 vectorized bf16 loads/stores (identical per-element math).
//   - flash_attn3: s_setprio(1) around QK / PV MFMA clusters (T5).
// ---------------------------------------------------------------------------

typedef __bf16 bf16_t;
typedef __bf16 bf16x4 __attribute__((ext_vector_type(4)));
typedef __bf16 bf16x8 __attribute__((ext_vector_type(8)));
typedef float f32x4 __attribute__((ext_vector_type(4)));

#define MFMA16(a, b, c) __builtin_amdgcn_mfma_f32_16x16x32_bf16(a, b, c, 0, 0, 0)

__device__ __forceinline__ void split_bf16(float x, bf16_t& h, bf16_t& l) {
    h = (bf16_t)x;
    l = (bf16_t)(x - (float)h);
}

typedef const __attribute__((address_space(1))) void glb_v;
typedef __attribute__((address_space(3))) void lds_v;

__device__ __forceinline__ void gl_lds16(const void* g, void* l) {
    __builtin_amdgcn_global_load_lds((glb_v*)g, (lds_v*)l, 16, 0, 0);
}
__device__ __forceinline__ void gl_lds4(const void* g, void* l) {
    __builtin_amdgcn_global_load_lds((glb_v*)g, (lds_v*)l, 4, 0, 0);
}

// ---------------------------------------------------------------------------
// Mixed block fake-quant of a [4096 x 4096] matrix -> integer codes + scales.
// 4 elements/thread.  OUT_I8: i8 codes (activations) vs bf16 codes (weights).
// Scales transposed: qsT[kb][row], kb = col/32.
// ---------------------------------------------------------------------------
template<int OUT_I8, int SPLIT, int GATHER>
__global__ void quant_is(const float* __restrict__ srcf,
                         const bf16_t* __restrict__ shi, const bf16_t* __restrict__ slo,
                         const int* __restrict__ rid,
                         signed char* __restrict__ qi8, bf16_t* __restrict__ qbf,
                         float* __restrict__ qsT) {
    long idx = ((long)blockIdx.x * 256 + threadIdx.x) << 2;
    int col = (int)(idx & 4095);
    long rowoff = idx & ~4095L;     // row * 4096
    float v[4];
    float a = 0.f;
    if (!GATHER && !SPLIT) {
        float4 f = *(const float4*)&srcf[idx];
        v[0] = f.x; v[1] = f.y; v[2] = f.z; v[3] = f.w;
#pragma unroll
        for (int j = 0; j < 4; ++j) a = fmaxf(a, fabsf(v[j]));
    } else {
#pragma unroll
        for (int j = 0; j < 4; ++j) {
            int g = GATHER ? rid[col + j] : col + j;
            float x = SPLIT ? ((float)shi[rowoff + g] + (float)slo[rowoff + g])
                            : srcf[rowoff + g];
            v[j] = x;
            a = fmaxf(a, fabsf(x));
        }
    }
    // 8 consecutive lanes cover one 32-elem block
#pragma unroll
    for (int off = 1; off < 8; off <<= 1) a = fmaxf(a, __shfl_xor(a, off, 64));
    float qmax = (col < 2560) ? 7.0f : (col < 3584 ? 31.0f : 127.0f);
    float scale = fmaxf(a / qmax, 1e-8f);
    float inv = 1.0f / scale;
    if (OUT_I8) {
        int pk = 0;
#pragma unroll
        for (int j = 0; j < 4; ++j) {
            float q = fminf(fmaxf(rintf(v[j] * inv), -qmax), qmax);
            pk |= (int)(unsigned char)(signed char)(int)q << (8 * j);
        }
        *(int*)&qi8[idx] = pk;
    } else {
        bf16x4 pk;
#pragma unroll
        for (int j = 0; j < 4; ++j) {
            float q = fminf(fmaxf(rintf(v[j] * inv), -qmax), qmax);
            pk[j] = (bf16_t)q;
        }
        *(bf16x4*)&qbf[idx] = pk;
    }
    if ((col & 31) == 0) qsT[((long)(col >> 5) << 12) + (idx >> 12)] = scale;
}

// ---------------------------------------------------------------------------
// GEMM C[4096,4096] = (As.Aq) * (Bs.Bq)^T, exact-int inner blocks.
// 128x128 tile, BK=32 (= one scale block).  Depth-2 pipeline, 3 LDS buffer
// sets, counted vmcnt(4).  LDS tiles XOR-swizzled: chunk ^= (row&3)<<4.
// ---------------------------------------------------------------------------
template<int OSPL>
__global__ __launch_bounds__(256, 2) void gemm_is(
    const signed char* __restrict__ Ai, const float* __restrict__ AsT,
    const bf16_t* __restrict__ Bi, const float* __restrict__ BsT,
    bf16_t* __restrict__ OHi, bf16_t* __restrict__ OLo, float* __restrict__ Of) {
    constexpr int K = 4096, N = 4096;
    __shared__ __align__(16) bf16_t sA[3][128 * 32];   // 8 KB each
    __shared__ __align__(16) bf16_t sB[3][128 * 32];   // 8 KB each
    __shared__ __align__(16) float  sS[3][256];        // [0,128) A, [128,256) B

    const int tid = threadIdx.x;
    const int bid = blockIdx.x;
    const int xcd = bid & 7, jj = bid >> 3;
    const int bx = xcd * 4 + (jj & 3), by = jj >> 2;
    const int rowBase = by << 7, colBase = bx << 7;
    const int lane = tid & 63, wave = tid >> 6;
    const int wr = (wave >> 1) << 6, wc = (wave & 1) << 6;
    const int n16 = lane & 15, quad = lane >> 4;

    // ---- staging geometry ----
    // A: thread owns row tid>>1, 16 i8 at col (tid&1)*16 -> 2 swizzled 16B chunks
    const int arow = tid >> 1, acb = (tid & 1) << 4;
    const long aSrc = (long)(rowBase + arow) * K + acb;
    const int aswz = (arow & 3) << 4;
    const int ac0 = (acb >> 3) << 4;                  // byte of first chunk
    const int aDst0 = arow * 64 + (ac0 ^ aswz);
    const int aDst1 = arow * 64 + ((ac0 + 16) ^ aswz);
    // B: linear LDS dest (DMA), pre-swizzled global source chunk
    const int brow = tid >> 2;
    const int bcs = (((tid & 3) ^ (brow & 3)) << 3);  // bf16 elems
    const long bSrc0 = (long)(colBase + brow) * K + bcs;
    const long bSrc1 = (long)(colBase + 64 + brow) * K + bcs;
    const int bDst = tid << 4;
    // scales
    const int sIsB = wave >> 1;
    const float* sPtr = (sIsB ? BsT + colBase : AsT + rowBase) + ((wave & 1) << 6) + lane;
    const int sDst = (sIsB ? 512 : 0) + ((wave & 1) << 8) + (lane << 2);

    f32x4 acc[4][4];
#pragma unroll
    for (int m = 0; m < 4; ++m)
#pragma unroll
        for (int n = 0; n < 4; ++n) acc[m][n] = (f32x4){0.f, 0.f, 0.f, 0.f};

    int4 aRegA, aRegB;

#define ISSUE(BUFI, KB, AR) do {                                              \
    char* _b = (char*)sB[BUFI];                                               \
    char* _s = (char*)sS[BUFI];                                               \
    const long _k0 = (long)(KB) << 5;                                         \
    gl_lds16(Bi + bSrc0 + _k0, _b + bDst);                                    \
    gl_lds16(Bi + bSrc1 + _k0, _b + 4096 + bDst);                             \
    gl_lds4(sPtr + ((long)(KB) << 12), _s + sDst);                            \
    AR = *(const int4*)(Ai + aSrc + _k0);                                     \
} while (0)

#define CVTW(BUFI, AR) do {                                                   \
    const signed char* _pc = (const signed char*)&AR;                         \
    bf16x8 _v0, _v1;                                                          \
    _Pragma("unroll")                                                         \
    for (int _j2 = 0; _j2 < 8; ++_j2) {                                       \
        _v0[_j2] = (bf16_t)(float)_pc[_j2];                                   \
        _v1[_j2] = (bf16_t)(float)_pc[8 + _j2];                               \
    }                                                                         \
    *(bf16x8*)((char*)sA[BUFI] + aDst0) = _v0;                                \
    *(bf16x8*)((char*)sA[BUFI] + aDst1) = _v1;                                \
} while (0)

#define WAITV(NN) asm volatile("s_waitcnt vmcnt(" #NN ")" ::: "memory")
#define BARR() do { asm volatile("s_waitcnt lgkmcnt(0)" ::: "memory");        \
    __builtin_amdgcn_s_barrier(); asm volatile("" ::: "memory"); } while (0)

#define COMPUTE(BUFI) do {                                                    \
    const char* _pA = (const char*)sA[BUFI];                                  \
    const char* _pB = (const char*)sB[BUFI];                                  \
    const float* _pS = sS[BUFI];                                              \
    const int _rsw = (n16 & 3) << 4;                                          \
    bf16x8 _a[4], _bv[4];                                                     \
    f32x4 _as[4];                                                             \
    float _bs[4];                                                             \
    _Pragma("unroll")                                                         \
    for (int _m = 0; _m < 4; ++_m) {                                          \
        _a[_m] = *(const bf16x8*)(_pA + (wr + (_m << 4) + n16) * 64           \
                                  + ((quad << 4) ^ _rsw));                    \
        _as[_m] = *(const f32x4*)(_pS + wr + (_m << 4) + (quad << 2));        \
    }                                                                         \
    _Pragma("unroll")                                                         \
    for (int _n = 0; _n < 4; ++_n) {                                          \
        _bv[_n] = *(const bf16x8*)(_pB + (wc + (_n << 4) + n16) * 64          \
                                   + ((quad << 4) ^ _rsw));                   \
        _bs[_n] = _pS[128 + wc + (_n << 4) + n16];                            \
    }                                                                         \
    const f32x4 _z = (f32x4){0.f, 0.f, 0.f, 0.f};                             \
    _Pragma("unroll")                                                         \
    for (int _m = 0; _m < 4; ++_m)                                            \
        _Pragma("unroll")                                                     \
        for (int _n = 0; _n < 4; ++_n) {                                      \
            f32x4 _sc = MFMA16(_a[_m], _bv[_n], _z);                          \
            float _bn = _bs[_n];                                              \
            _Pragma("unroll")                                                 \
            for (int _r = 0; _r < 4; ++_r)                                    \
                acc[_m][_n][_r] = fmaf(_as[_m][_r] * _bn, _sc[_r],            \
                                       acc[_m][_n][_r]);                      \
        }                                                                     \
} while (0)

    // prologue: tiles 0,1 in flight; publish tile 0
    ISSUE(0, 0, aRegA);
    ISSUE(1, 1, aRegB);
    WAITV(4);
    CVTW(0, aRegA);
    BARR();

    int bc = 0;   // LDS buffer of current kb
    for (int kb = 0; kb < 128; kb += 2) {
        int b1 = bc + 1; if (b1 >= 3) b1 -= 3;
        int b2 = bc + 2; if (b2 >= 3) b2 -= 3;
        // even step kb: issue kb+2 -> aRegA, compute bc, publish kb+1 (aRegB)
        if (kb + 2 < 128) {
            ISSUE(b2, kb + 2, aRegA);
            COMPUTE(bc);
            WAITV(4);
        } else {
            COMPUTE(bc);
            WAITV(0);
        }
        CVTW(b1, aRegB);
        BARR();
        // odd step kb+1: issue kb+3 -> aRegB, compute b1, publish kb+2 (aRegA)
        if (kb + 3 < 128) {
            ISSUE(bc, kb + 3, aRegB);      // buf (kb+3)%3 == bc
            COMPUTE(b1);
            WAITV(4);
            CVTW(b2, aRegA);
            BARR();
        } else {
            COMPUTE(b1);                    // kb+1 == 127: last tile
        }
        bc = b2;
    }
#undef ISSUE
#undef CVTW
#undef WAITV
#undef BARR
#undef COMPUTE

#pragma unroll
    for (int m = 0; m < 4; ++m)
#pragma unroll
        for (int n = 0; n < 4; ++n) {
            int row = rowBase + wr + (m << 4) + (quad << 2);
            int col = colBase + wc + (n << 4) + n16;
#pragma unroll
            for (int r = 0; r < 4; ++r) {
                if (OSPL) {
                    bf16_t h, l;
                    split_bf16(acc[m][n][r], h, l);
                    OHi[(long)(row + r) * N + col] = h;
                    OLo[(long)(row + r) * N + col] = l;
                } else {
                    Of[(long)(row + r) * N + col] = acc[m][n][r];
                }
            }
        }
}

// ---------------------------------------------------------------------------
// RoPE in place on split q,k -- x8 vectorized, per-element math unchanged.
// ---------------------------------------------------------------------------
__global__ void rope2(bf16_t* __restrict__ qh, bf16_t* __restrict__ ql,
                      bf16_t* __restrict__ kh, bf16_t* __restrict__ kl,
                      const int* __restrict__ pos) {
    int t = blockIdx.x;
    int tid = threadIdx.x;
    __shared__ float cs[64], sn[64];
    if (tid < 64) {
        float invf = (float)pow(10000.0, -(double)tid / 64.0);
        float ang = (float)pos[t] * invf;
        cs[tid] = (float)cos((double)ang);
        sn[tid] = (float)sin((double)ang);
    }
    __syncthreads();
    const int hh = tid >> 3, d0 = (tid & 7) << 3;
    const long base = (long)t * 4096 + hh * 128 + d0;
    bf16x8 q0 = *(const bf16x8*)&qh[base],      q1 = *(const bf16x8*)&qh[base + 64];
    bf16x8 ql0 = *(const bf16x8*)&ql[base],     ql1 = *(const bf16x8*)&ql[base + 64];
    bf16x8 k0 = *(const bf16x8*)&kh[base],      k1 = *(const bf16x8*)&kh[base + 64];
    bf16x8 kl0 = *(const bf16x8*)&kl[base],     kl1 = *(const bf16x8*)&kl[base + 64];
    bf16x8 oqh0, oqh1, oql0, oql1, okh0, okh1, okl0, okl1;
#pragma unroll
    for (int j = 0; j < 8; ++j) {
        float c = cs[d0 + j], s = sn[d0 + j];
        float a0 = (float)q0[j] + (float)ql0[j];
        float a1 = (float)q1[j] + (float)ql1[j];
        float r0 = a0 * c - a1 * s, r1 = a1 * c + a0 * s;
        bf16_t x, y;
        split_bf16(r0, x, y); oqh0[j] = x; oql0[j] = y;
        split_bf16(r1, x, y); oqh1[j] = x; oql1[j] = y;
        float b0 = (float)k0[j] + (float)kl0[j];
        float b1 = (float)k1[j] + (float)kl1[j];
        r0 = b0 * c - b1 * s; r1 = b1 * c + b0 * s;
        split_bf16(r0, x, y); okh0[j] = x; okl0[j] = y;
        split_bf16(r1, x, y); okh1[j] = x; okl1[j] = y;
    }
    *(bf16x8*)&qh[base] = oqh0;      *(bf16x8*)&qh[base + 64] = oqh1;
    *(bf16x8*)&ql[base] = oql0;      *(bf16x8*)&ql[base + 64] = oql1;
    *(bf16x8*)&kh[base] = okh0;      *(bf16x8*)&kh[base + 64] = okh1;
    *(bf16x8*)&kl[base] = okl0;      *(bf16x8*)&kl[base + 64] = okl1;
}

// ---------------------------------------------------------------------------
// Transpose split V [tok, h*128+d] -> vT[(b*32+h)*128+d][s], both planes.
// uint4 global I/O both sides; LDS rows padded to 72 ushorts, 16B chunks
// XOR-swizzled by ((r>>3)&7)<<4 so the column-read phase is conflict-free.
// ---------------------------------------------------------------------------
__global__ void transpose_vt(const ushort* __restrict__ vh, const ushort* __restrict__ vl,
                             ushort* __restrict__ th, ushort* __restrict__ tl) {
    __shared__ __align__(16) ushort t0[64 * 72];
    __shared__ __align__(16) ushort t1[64 * 72];
    const int ct = blockIdx.x, tt = blockIdx.y, tid = threadIdx.x;
    // ---- load: 512 chunks (16B) per plane, 2 per thread per plane ----
#pragma unroll
    for (int i = 0; i < 2; ++i) {
        int cid = i * 256 + tid;
        int r = cid >> 3, c8 = cid & 7;
        long g = (long)(tt * 64 + r) * 4096 + ct * 64 + c8 * 8;
        int d = r * 144 + ((c8 << 4) ^ (((r >> 3) & 7) << 4));
        *(uint4*)((char*)t0 + d) = *(const uint4*)&vh[g];
        *(uint4*)((char*)t1 + d) = *(const uint4*)&vl[g];
    }
    __syncthreads();
    // ---- store: lane owns (dr, 8 toks); column-read from LDS, uint4 out ----
#pragma unroll
    for (int i = 0; i < 2; ++i) {
        int cid = i * 256 + tid;
        int dr = cid >> 3, s8 = cid & 7;
        int colg = ct * 64 + dr, hh = colg >> 7, dl = colg & 127;
        int tok0 = tt * 64 + s8 * 8, b = tok0 >> 11, s = tok0 & 2047;
        long o = (long)((b * 32 + hh) * 128 + dl) * 2048 + s;
        ushort u0[8], u1[8];
#pragma unroll
        for (int jk = 0; jk < 8; ++jk) {
            int r = s8 * 8 + jk;
            int byt = r * 144 + (((dr >> 3) << 4) ^ (((r >> 3) & 7) << 4)) + (dr & 7) * 2;
            u0[jk] = *(const ushort*)((const char*)t0 + byt);
            u1[jk] = *(const ushort*)((const char*)t1 + byt);
        }
        *(uint4*)&th[o] = *(const uint4*)u0;
        *(uint4*)&tl[o] = *(const uint4*)u1;
    }
}

// ---------------------------------------------------------------------------
// Causal flash attention, 2-phase pipelined (R4 structure + T5 setprio).
// ---------------------------------------------------------------------------
__global__ __launch_bounds__(256, 2) void flash_attn3(
    const bf16_t* __restrict__ qhp, const bf16_t* __restrict__ qlp,
    const bf16_t* __restrict__ khp, const bf16_t* __restrict__ klp,
    const bf16_t* __restrict__ vth, const bf16_t* __restrict__ vtl,
    bf16_t* __restrict__ ohi, bf16_t* __restrict__ olo) {
    __shared__ __align__(16) char smem[75776];

    const int bid = blockIdx.x;
    const int xcd = bid & 7, ixd = bid >> 3;
    const int bh = (xcd << 3) + (ixd >> 4);
    const int qt = 15 - (ixd & 15);
    const int b = bh >> 5, h = bh & 31;
    const int tid = threadIdx.x;
    const int wave = tid >> 6, lane = tid & 63;
    const int n16 = lane & 15, quad = lane >> 4;
    const long tokB = (long)b * 2048;
    const int q0 = qt * 128 + wave * 32;
    const float scale = 0.08838834764831845f;   // 1/sqrt(128)

    bf16_t (*pH)[40] = (bf16_t (*)[40])(smem + 65536 + wave * 2560);
    bf16_t (*pL)[40] = (bf16_t (*)[40])(smem + 65536 + wave * 2560 + 1280);

    bf16x8 qhF[2][4], qlF[2][4];
#pragma unroll
    for (int m = 0; m < 2; ++m) {
        long qoff = (tokB + q0 + m * 16 + n16) * 4096 + h * 128 + quad * 8;
#pragma unroll
        for (int f = 0; f < 4; ++f) {
            qhF[m][f] = *(const bf16x8*)&qhp[qoff + f * 32];
            qlF[m][f] = *(const bf16x8*)&qlp[qoff + f * 32];
        }
    }

    const int kr0 = wave * 8 + quad;
    const int kc0 = ((((lane & 15) << 4) ^ (quad << 4)) >> 1);
    const int kc1 = ((((lane & 15) << 4) ^ ((4 + quad) << 4)) >> 1);
    const int kd0 = kr0 * 256 + ((lane & 15) << 4);
    const int vr0 = wave * 32 + (lane >> 2);
    const int vc0 = ((((lane & 3) << 4) ^ (((lane >> 2) & 3) << 4)) >> 1);
    const int vd0 = vr0 * 64 + ((lane & 3) << 4);
    const long vrow_g = (long)(bh * 128 + vr0) * 2048;

#define STAGE(BUF, KB) do {                                                   \
    char* _bb = smem + ((BUF) << 15);                                         \
    const long _kt = tokB + (long)(KB) * 32;                                  \
    const long _g0 = (_kt + kr0) * 4096 + h * 128;                            \
    gl_lds16(khp + _g0 + kc0,           _bb + kd0);                           \
    gl_lds16(klp + _g0 + kc0,           _bb + 8192 + kd0);                    \
    gl_lds16(khp + _g0 + 4 * 4096 + kc1, _bb + 1024 + kd0);                   \
    gl_lds16(klp + _g0 + 4 * 4096 + kc1, _bb + 8192 + 1024 + kd0);            \
    const long _v0 = vrow_g + (KB) * 32 + vc0;                                \
    gl_lds16(vth + _v0,                 _bb + 16384 + vd0);                   \
    gl_lds16(vtl + _v0,                 _bb + 24576 + vd0);                   \
    gl_lds16(vth + _v0 + 16 * 2048,     _bb + 16384 + 1024 + vd0);            \
    gl_lds16(vtl + _v0 + 16 * 2048,     _bb + 24576 + 1024 + vd0);            \
} while (0)

    f32x4 o[2][8];
#pragma unroll
    for (int m = 0; m < 2; ++m)
#pragma unroll
        for (int dc = 0; dc < 8; ++dc) o[m][dc] = (f32x4){0.f, 0.f, 0.f, 0.f};
    float m_i[2][4], l_i[2][4];
#pragma unroll
    for (int m = 0; m < 2; ++m)
#pragma unroll
        for (int r = 0; r < 4; ++r) { m_i[m][r] = -1e30f; l_i[m][r] = 0.f; }

    const int nkb = 4 * qt + 4;
    const int lastkb = 4 * qt + wave;

    STAGE(0, 0);
    asm volatile("s_waitcnt vmcnt(0)" ::: "memory");
    __builtin_amdgcn_s_barrier();
    asm volatile("" ::: "memory");

    for (int kb = 0; kb < nkb; ++kb) {
        if (kb + 1 < nkb) STAGE((kb + 1) & 1, kb + 1);

        if (kb <= lastkb) {
            const char* bK = smem + ((kb & 1) << 15);
            const char* bV = bK + 16384;

            f32x4 s[2][2];
            const int rswz = (n16 & 7) << 4;
            __builtin_amdgcn_s_setprio(1);
#pragma unroll
            for (int nt = 0; nt < 2; ++nt) {
                const int krow = nt * 16 + n16;
                bf16x8 kh[4], kl[4];
#pragma unroll
                for (int f = 0; f < 4; ++f) {
                    const int cb = ((f << 6) | (quad << 4)) ^ rswz;
                    kh[f] = *(const bf16x8*)(bK + krow * 256 + cb);
                    kl[f] = *(const bf16x8*)(bK + 8192 + krow * 256 + cb);
                }
#pragma unroll
                for (int m = 0; m < 2; ++m) {
                    f32x4 sc = (f32x4){0.f, 0.f, 0.f, 0.f};
#pragma unroll
                    for (int f = 0; f < 4; ++f) {
                        sc = MFMA16(qhF[m][f], kh[f], sc);
                        sc = MFMA16(qhF[m][f], kl[f], sc);
                        sc = MFMA16(qlF[m][f], kh[f], sc);
                    }
                    s[m][nt] = sc;
                }
            }
            __builtin_amdgcn_s_setprio(0);

            if (kb == lastkb) {
                const int key0 = kb * 32 + n16;
#pragma unroll
                for (int m = 0; m < 2; ++m)
#pragma unroll
                    for (int nt = 0; nt < 2; ++nt)
#pragma unroll
                        for (int r = 0; r < 4; ++r) {
                            int qrow = q0 + m * 16 + quad * 4 + r;
                            s[m][nt][r] = (key0 + nt * 16 <= qrow) ? s[m][nt][r] * scale
                                                                   : -1e30f;
                        }
            } else {
#pragma unroll
                for (int m = 0; m < 2; ++m)
#pragma unroll
                    for (int nt = 0; nt < 2; ++nt)
#pragma unroll
                        for (int r = 0; r < 4; ++r) s[m][nt][r] *= scale;
            }

            float alpha[2][4];
#pragma unroll
            for (int m = 0; m < 2; ++m)
#pragma unroll
                for (int r = 0; r < 4; ++r) {
                    float mx = fmaxf(s[m][0][r], s[m][1][r]);
#pragma unroll
                    for (int off = 1; off < 16; off <<= 1) mx = fmaxf(mx, __shfl_xor(mx, off, 64));
                    float mnew = fmaxf(m_i[m][r], mx);
                    alpha[m][r] = expf(m_i[m][r] - mnew);
                    m_i[m][r] = mnew;
                    float p0 = expf(s[m][0][r] - mnew);
                    float p1 = expf(s[m][1][r] - mnew);
                    s[m][0][r] = p0;
                    s[m][1][r] = p1;
                    float sum = p0 + p1;
#pragma unroll
                    for (int off = 1; off < 16; off <<= 1) sum += __shfl_xor(sum, off, 64);
                    l_i[m][r] = l_i[m][r] * alpha[m][r] + sum;
                }

            bf16x8 ph2[2], pl2[2];
#pragma unroll
            for (int m = 0; m < 2; ++m) {
#pragma unroll
                for (int nt = 0; nt < 2; ++nt)
#pragma unroll
                    for (int r = 0; r < 4; ++r) {
                        bf16_t hh2, ll2;
                        split_bf16(s[m][nt][r], hh2, ll2);
                        pH[quad * 4 + r][nt * 16 + n16] = hh2;
                        pL[quad * 4 + r][nt * 16 + n16] = ll2;
                    }
                ph2[m] = *(const bf16x8*)&pH[n16][quad * 8];
                pl2[m] = *(const bf16x8*)&pL[n16][quad * 8];
            }

            __builtin_amdgcn_s_setprio(1);
#pragma unroll
            for (int dc = 0; dc < 8; ++dc) {
                const int vrow = dc * 16 + n16;
                const int vcb = ((quad ^ (n16 & 3)) << 4);
                bf16x8 vh = *(const bf16x8*)(bV + vrow * 64 + vcb);
                bf16x8 vl = *(const bf16x8*)(bV + 8192 + vrow * 64 + vcb);
#pragma unroll
                for (int m = 0; m < 2; ++m) {
#pragma unroll
                    for (int r = 0; r < 4; ++r) o[m][dc][r] *= alpha[m][r];
                    o[m][dc] = MFMA16(ph2[m], vh, o[m][dc]);
                    o[m][dc] = MFMA16(ph2[m], vl, o[m][dc]);
                    o[m][dc] = MFMA16(pl2[m], vh, o[m][dc]);
                }
            }
            __builtin_amdgcn_s_setprio(0);
        }

        asm volatile("s_waitcnt vmcnt(0)" ::: "memory");
        __builtin_amdgcn_s_barrier();
        asm volatile("" ::: "memory");
    }
#undef STAGE

#pragma unroll
    for (int m = 0; m < 2; ++m)
#pragma unroll
        for (int r = 0; r < 4; ++r) {
            float invl = 1.0f / l_i[m][r];
            long row = tokB + q0 + m * 16 + quad * 4 + r;
#pragma unroll
            for (int dc = 0; dc < 8; ++dc) {
                bf16_t hh2, ll2;
                split_bf16(o[m][dc][r] * invl, hh2, ll2);
                ohi[row * 4096 + h * 128 + dc * 16 + n16] = hh2;
                olo[row * 4096 + h * 128 + dc * 16 + n16] = ll2;
            }
        }
}

// ---------------------------------------------------------------------------
// Launcher.  ws (192 MB):
//   [  0.. 32) QH   [ 32.. 64) QL   [ 64.. 96) KH   [ 96..128) KL
//   phase 1 (QKV): Xi i8 @128..144, XsT @144..146, WsT @146..148,
//                  Wi bf16 @160..192;  v-split -> d_out
//   phase 2: VT @128..192 (VTh@128, VTl@160); flash -> d_out (attn split)
//   phase 3 (Wo): Xi2 i8 @64..80 (K dead), Xs2T @96..98,
//                 Wo bf16 @128..160, WoST @160..162; gemm -> d_out fp32
// ---------------------------------------------------------------------------
extern "C" void kernel_launch(void* const* d_in, const int* in_sizes, int n_in,
                              void* d_out, int out_size, void* d_ws, size_t ws_size,
                              hipStream_t stream) {
    const float* x  = (const float*)d_in[0];
    const float* Wq = (const float*)d_in[1];
    const float* Wk = (const float*)d_in[2];
    const float* Wv = (const float*)d_in[3];
    const float* Wo = (const float*)d_in[4];
    const int* pos  = (const int*)d_in[5];
    const int* rid  = (const int*)d_in[6];

    const size_t MB = 1024ull * 1024ull;
    char* ws = (char*)d_ws;
    bf16_t* QH = (bf16_t*)(ws);
    bf16_t* QL = (bf16_t*)(ws + 32 * MB);
    bf16_t* KH = (bf16_t*)(ws + 64 * MB);
    bf16_t* KL = (bf16_t*)(ws + 96 * MB);
    signed char* Xi = (signed char*)(ws + 128 * MB);
    float*  XsT = (float*)(ws + 144 * MB);
    float*  WsT = (float*)(ws + 146 * MB);
    bf16_t* Wi  = (bf16_t*)(ws + 160 * MB);
    bf16_t* VTh = (bf16_t*)(ws + 128 * MB);
    bf16_t* VTl = (bf16_t*)(ws + 160 * MB);
    signed char* Xi2 = (signed char*)(ws + 64 * MB);
    float*  Xs2T = (float*)(ws + 96 * MB);
    bf16_t* Wo_i = (bf16_t*)(ws + 128 * MB);
    float*  WoST = (float*)(ws + 160 * MB);
    bf16_t* OUh = (bf16_t*)d_out;
    bf16_t* OUl = (bf16_t*)((char*)d_out + 32 * MB);

    const int QG = 16384;

    // ---- quantize x once (i8 + transposed scales) ----
    quant_is<1, 0, 1><<<QG, 256, 0, stream>>>(x, nullptr, nullptr, rid, Xi, nullptr, XsT);

    // ---- q = xq @ Wq^T ----
    quant_is<0, 0, 0><<<QG, 256, 0, stream>>>(Wq, nullptr, nullptr, rid, nullptr, Wi, WsT);
    gemm_is<1><<<1024, 256, 0, stream>>>(Xi, XsT, Wi, WsT, QH, QL, nullptr);
    // ---- k ----
    quant_is<0, 0, 0><<<QG, 256, 0, stream>>>(Wk, nullptr, nullptr, rid, nullptr, Wi, WsT);
    gemm_is<1><<<1024, 256, 0, stream>>>(Xi, XsT, Wi, WsT, KH, KL, nullptr);
    // ---- v (into d_out scratch) ----
    quant_is<0, 0, 0><<<QG, 256, 0, stream>>>(Wv, nullptr, nullptr, rid, nullptr, Wi, WsT);
    gemm_is<1><<<1024, 256, 0, stream>>>(Xi, XsT, Wi, WsT, OUh, OUl, nullptr);

    rope2<<<4096, 256, 0, stream>>>(QH, QL, KH, KL, pos);

    transpose_vt<<<dim3(64, 64), 256, 0, stream>>>((const ushort*)OUh, (const ushort*)OUl,
                                                   (ushort*)VTh, (ushort*)VTl);

    flash_attn3<<<1024, 256, 0, stream>>>(QH, QL, KH, KL, VTh, VTl, OUh, OUl);

    // ---- out = attnq @ Wo^T (fp32 direct into d_out) ----
    quant_is<1, 1, 1><<<QG, 256, 0, stream>>>(nullptr, OUh, OUl, rid, Xi2, nullptr, Xs2T);
    quant_is<0, 0, 0><<<QG, 256, 0, stream>>>(Wo, nullptr, nullptr, rid, nullptr, Wo_i, WoST);
    gemm_is<0><<<1024, 256, 0, stream>>>(Xi2, Xs2T, Wo_i, WoST, nullptr, nullptr, (float*)d_out);

    (void)in_sizes; (void)n_in; (void)out_size; (void)ws_size;
}